// Round 3
// baseline (604.305 us; speedup 1.0000x reference)
//
#include <hip/hip_runtime.h>
#include <cstdint>
#include <cstddef>

#define T_LEN 2048
#define PAST_MAX 2048
#define HID 4096
#define NHEAD 32
#define DHEAD 128

typedef __bf16 bf16_t;
typedef __bf16 bf16x4 __attribute__((ext_vector_type(4)));
typedef __bf16 bf16x8 __attribute__((ext_vector_type(8)));
typedef float  f32x4  __attribute__((ext_vector_type(4)));
typedef float  f32x16 __attribute__((ext_vector_type(16)));
typedef unsigned int u32x4 __attribute__((ext_vector_type(4)));

__device__ __forceinline__ void gload16(const void* g, void* l){
  __builtin_amdgcn_global_load_lds((const __attribute__((address_space(1))) void*)g,
                                   (__attribute__((address_space(3))) void*)l,
                                   16, 0, 0);
}

__device__ __forceinline__ unsigned pack_bf16(float a, float b){
  const unsigned ua = __builtin_bit_cast(unsigned short, (bf16_t)a);
  const unsigned ub = __builtin_bit_cast(unsigned short, (bf16_t)b);
  return ua | (ub << 16);
}

// ---------------- fused f32 -> bf16 for X and past_k ----------------
__global__ void cvt2_k(const float* __restrict__ a, bf16_t* __restrict__ ao,
                       const float* __restrict__ b, bf16_t* __restrict__ bo, int n4){
  int i = blockIdx.x * 256 + threadIdx.x;
  if (i < n4){
    const float4 v = ((const float4*)a)[i];
    bf16x4 o = { (bf16_t)v.x, (bf16_t)v.y, (bf16_t)v.z, (bf16_t)v.w };
    ((bf16x4*)ao)[i] = o;
  } else {
    i -= n4;
    const float4 v = ((const float4*)b)[i];
    bf16x4 o = { (bf16_t)v.x, (bf16_t)v.y, (bf16_t)v.z, (bf16_t)v.w };
    ((bf16x4*)bo)[i] = o;
  }
}

// ---------------- f32 [B][R][C] -> bf16 [B][C][R], 64x64 tiles ----------------
__global__ __launch_bounds__(256) void transpose2_k(const float* __restrict__ in,
                                                    bf16_t* __restrict__ out, int R, int C){
  __shared__ float tile[64][65];
  const int r0 = blockIdx.x << 6, c0 = blockIdx.y << 6;
  const size_t bo = (size_t)blockIdx.z * (size_t)R * (size_t)C;
  const int tx = threadIdx.x & 15, ty = threadIdx.x >> 4;
#pragma unroll
  for (int k = 0; k < 4; ++k){
    const float4 v = *(const float4*)(in + bo + (size_t)(r0 + ty + 16*k) * C + c0 + tx*4);
    float* tp = &tile[ty + 16*k][tx*4];
    tp[0] = v.x; tp[1] = v.y; tp[2] = v.z; tp[3] = v.w;
  }
  __syncthreads();
  const int rr0 = (threadIdx.x & 7) * 8;
  const int ccb = threadIdx.x >> 3;     // 0..31
#pragma unroll
  for (int k = 0; k < 2; ++k){
    const int cc = ccb + 32*k;
    bf16x8 o;
#pragma unroll
    for (int j = 0; j < 8; ++j) o[j] = (bf16_t)tile[rr0 + j][cc];
    *(bf16x8*)(out + bo + (size_t)(c0 + cc) * R + r0 + rr0) = o;
  }
}

// ---------------- fused transpose of Wq/Wk/Wv (z selects) ----------------
__global__ __launch_bounds__(256) void transpose3_k(
    const float* __restrict__ s0, const float* __restrict__ s1, const float* __restrict__ s2,
    bf16_t* __restrict__ d0, bf16_t* __restrict__ d1, bf16_t* __restrict__ d2){
  __shared__ float tile[64][65];
  const float* in = (blockIdx.z == 0) ? s0 : (blockIdx.z == 1) ? s1 : s2;
  bf16_t* out = (blockIdx.z == 0) ? d0 : (blockIdx.z == 1) ? d1 : d2;
  const int r0 = blockIdx.x << 6, c0 = blockIdx.y << 6;
  const int tx = threadIdx.x & 15, ty = threadIdx.x >> 4;
#pragma unroll
  for (int k = 0; k < 4; ++k){
    const float4 v = *(const float4*)(in + (size_t)(r0 + ty + 16*k) * HID + c0 + tx*4);
    float* tp = &tile[ty + 16*k][tx*4];
    tp[0] = v.x; tp[1] = v.y; tp[2] = v.z; tp[3] = v.w;
  }
  __syncthreads();
  const int rr0 = (threadIdx.x & 7) * 8;
  const int ccb = threadIdx.x >> 3;
#pragma unroll
  for (int k = 0; k < 2; ++k){
    const int cc = ccb + 32*k;
    bf16x8 o;
#pragma unroll
    for (int j = 0; j < 8; ++j) o[j] = (bf16_t)tile[rr0 + j][cc];
    *(bf16x8*)(out + (size_t)(c0 + cc) * HID + r0 + rr0) = o;
  }
}

// ---------------- RoPE in place on K only (Q roped in-register inside attn) ------------
__global__ void ropek_k(bf16_t* __restrict__ K, const int* __restrict__ pos){
  const int idx = blockIdx.x * 256 + threadIdx.x;     // 32*2048*64 total
  const int i = idx & 63;
  const int t = (idx >> 6) & (T_LEN - 1);
  const int h = idx >> 17;
  const size_t base = ((size_t)h * T_LEN + t) * DHEAD;
  const float p = (float)pos[t];
  const float inv = __expf(-(float)i * 0.14391156605212898f);  // ln(10000)/64
  const float ang = p * inv;
  float sn, cs;
  sincosf(ang, &sn, &cs);
  const float b0 = (float)K[base + i], b1 = (float)K[base + i + 64];
  K[base + i]      = (bf16_t)(b0 * cs - b1 * sn);
  K[base + i + 64] = (bf16_t)(b1 * cs + b0 * sn);
}

// ------------- QKV: 256x256 BK=32, 4-deep LDS ring, 3-tile prefetch lead --------------
// R0/R1/R2 post-mortem: every 1-phase-lead schedule ties at ~750-830 TF; the stall is
// the tile-boundary wait on loads issued ~1 phase (~200cy) earlier vs 200-900cy memory
// latency. This kernel gives every load a 6-phase (~1200cy) lead: ring of 4 x 32KB tiles,
// tile kt+3 staged during tile kt (2 gloads/phase), steady-state wait = vmcnt(8) once per
// tile (retires kt+1; kt+2/kt+3 stay in flight). Never drains in main loop.
// 8 waves 2Mx4N (wave tile 128x64); per tile 2 phases x 16 MFMA.
// LDS tile: A[256r x 32k] + B[256r x 32k], rows packed 2-per-128B line, chunk j of row
// stored at j^(drow&3) -> frag reads 8 distinct bank-starts x 2 lanes = conflict-free.
// WAR: stage(kt+3) overwrites kt-1's region; kt-1 reads are lgkm-drained before the
// tile-end barrier every wave passed. RAW: vmcnt(8)+barrier publishes kt+1.
__global__ __launch_bounds__(512, 1) void gemmqkv8p_k(
    const bf16_t* __restrict__ A,
    const bf16_t* __restrict__ B0, const bf16_t* __restrict__ B1, const bf16_t* __restrict__ B2,
    bf16_t* __restrict__ OQ, bf16_t* __restrict__ OK2, bf16_t* __restrict__ OVT, int cpx)
{
  const int bid = blockIdx.x;
  const int wg  = (bid & 7) * cpx + (bid >> 3);   // cpx = 48, 384 % 8 == 0 -> bijective
  const int mt  = wg & 7;            // 8 M-tiles of 256
  const int nt  = wg >> 3;           // 0..47 N-tiles of 256 (12288 cols over 3 matrices)
  const int z   = nt >> 4;           // matrix select
  const int m0  = mt << 8;
  const int n0  = (nt & 15) << 8;
  const bf16_t* __restrict__ B = (z == 0) ? B0 : (z == 1) ? B1 : B2;

  const int tid = threadIdx.x;
  const int wv = tid >> 6, lane = tid & 63, lm = lane & 15, g = lane >> 4;
  const int wr = wv >> 2, wc = wv & 3;      // 2 M-groups x 4 N-groups (wave tile 128x64)

  __shared__ __align__(16) char smem[131072];   // ring: 4 tiles x (A 16K + B 16K)

  const f32x4 fzero = {0.f, 0.f, 0.f, 0.f};
  f32x4 acc[8][4];
#pragma unroll
  for (int i = 0; i < 8; ++i)
#pragma unroll
    for (int j = 0; j < 4; ++j) acc[i][j] = fzero;

  // staging decode: unit (A or B part of a tile) = 16KB = 1024 chunks; 2 loads/thread.
  // LDS chunk c at byte c*16; layout: double-row d=c>>3 (128B), cc=c&7:
  //   row = 2d + (cc>>2), stored position holds logical chunk j = (cc&3)^(d&3).
  size_t soff[2];
#pragma unroll
  for (int i = 0; i < 2; ++i){
    const int c = i * 512 + tid;
    const int d = c >> 3, cc = c & 7;
    soff[i] = (size_t)(2 * d + (cc >> 2)) * HID + (size_t)((((cc & 3) ^ (d & 3)) << 3));
  }
  const bf16_t* Abase = A + (size_t)m0 * HID;
  const bf16_t* Bbase = B + (size_t)n0 * HID;
  const int ldst0 = ((0 * 512 + wv * 64) << 4);
  const int ldst1 = ((1 * 512 + wv * 64) << 4);

  auto stgA = [&](int kt){
    char* tb = smem + (kt & 3) * 32768;
    const bf16_t* src = Abase + (size_t)kt * 32;
    gload16(src + soff[0], tb + ldst0);
    gload16(src + soff[1], tb + ldst1);
  };
  auto stgB = [&](int kt){
    char* tb = smem + (kt & 3) * 32768 + 16384;
    const bf16_t* src = Bbase + (size_t)kt * 32;
    gload16(src + soff[0], tb + ldst0);
    gload16(src + soff[1], tb + ldst1);
  };

  // fragment read constants: row r -> byte (r>>1)*128 + (r&1)*64 + ((g^((r>>1)&3))<<4)
  // frag rows: r = base16*mf + lm -> (r>>1)&3 == (lm>>1)&3 (lane-constant)
  const int fsw = (((g ^ ((lm >> 1) & 3)) << 4)) + ((lm & 1) << 6) + ((lm >> 1) << 7);
  const int aB_ = (wr << 13) + fsw;              // + mf*1024
  const int bB_ = 16384 + (wc << 12) + fsw;      // + ni*1024

  // prologue: tiles 0,1,2 fully staged; retire tile 0, keep 1,2 in flight
  stgA(0); stgB(0); stgA(1); stgB(1); stgA(2); stgB(2);
  asm volatile("s_waitcnt vmcnt(8)" ::: "memory");
  __builtin_amdgcn_s_barrier();

  for (int kt = 0; kt < 128; ++kt){
    const char* tb = smem + (kt & 3) * 32768;

    // ---- phase A: read B-frags + A-frags mf0-3; stage A-part of kt+3 ----
    bf16x8 bfr[4], afr[4];
#pragma unroll
    for (int ni = 0; ni < 4; ++ni) bfr[ni] = *(const bf16x8*)(tb + bB_ + ni * 1024);
#pragma unroll
    for (int mf = 0; mf < 4; ++mf) afr[mf] = *(const bf16x8*)(tb + aB_ + mf * 1024);
    if (kt < 125) stgA(kt + 3);
    __builtin_amdgcn_s_barrier();
    asm volatile("s_waitcnt lgkmcnt(0)" ::: "memory");
    __builtin_amdgcn_s_setprio(1);
#pragma unroll
    for (int mf = 0; mf < 4; ++mf)
#pragma unroll
      for (int ni = 0; ni < 4; ++ni)
        acc[mf][ni] = __builtin_amdgcn_mfma_f32_16x16x32_bf16(afr[mf], bfr[ni], acc[mf][ni], 0, 0, 0);
    __builtin_amdgcn_s_setprio(0);

    // ---- phase B: read A-frags mf4-7; stage B-part of kt+3; publish kt+1 ----
    bf16x8 afr2[4];
#pragma unroll
    for (int mf = 0; mf < 4; ++mf) afr2[mf] = *(const bf16x8*)(tb + aB_ + (mf + 4) * 1024);
    if (kt < 125) stgB(kt + 3);
    asm volatile("s_waitcnt lgkmcnt(0)" ::: "memory");   // all tile-kt reads done pre-barrier (WAR)
    if (kt < 125)       asm volatile("s_waitcnt vmcnt(8)" ::: "memory");   // kt+1 landed
    else if (kt == 125) asm volatile("s_waitcnt vmcnt(4)" ::: "memory");
    else                asm volatile("s_waitcnt vmcnt(0)" ::: "memory");
    __builtin_amdgcn_s_barrier();
    __builtin_amdgcn_s_setprio(1);
#pragma unroll
    for (int mf = 0; mf < 4; ++mf)
#pragma unroll
      for (int ni = 0; ni < 4; ++ni)
        acc[mf + 4][ni] = __builtin_amdgcn_mfma_f32_16x16x32_bf16(afr2[mf], bfr[ni], acc[mf + 4][ni], 0, 0, 0);
    __builtin_amdgcn_s_setprio(0);
  }

  // epilogue: 3-way layout select (Q/K [H][T][D], V^T [H][D][T])
#pragma unroll
  for (int ni = 0; ni < 4; ++ni){
    const int col = n0 + wc * 64 + ni * 16 + lm;
    const int hh = col >> 7, dd = col & 127;
#pragma unroll
    for (int mf = 0; mf < 8; ++mf)
#pragma unroll
      for (int r = 0; r < 4; ++r){
        const int trow = m0 + wr * 128 + mf * 16 + g * 4 + r;
        const bf16_t v = (bf16_t)acc[mf][ni][r];
        if (z == 2)      OVT[((size_t)hh * DHEAD + dd) * T_LEN + trow] = v;
        else if (z == 1) OK2[((size_t)hh * T_LEN + trow) * DHEAD + dd] = v;
        else             OQ [((size_t)hh * T_LEN + trow) * DHEAD + dd] = v;
      }
  }
}

// ------------- out-proj: 256x128 4-phase interleaved GEMM (R15-proven, 4Mx2N) ----------
__global__ __launch_bounds__(512, 1) void gemm4p_k(
    const bf16_t* __restrict__ A, const bf16_t* __restrict__ B,
    float* __restrict__ OF, int cpx)
{
  const int bid = blockIdx.x;
  const int wg  = (bid & 7) * cpx + (bid >> 3);
  const int mt  = wg & 7;
  const int nt  = wg >> 3;
  const int m0  = mt << 8;
  const int n0  = nt << 7;

  const int tid = threadIdx.x;
  const int wv = tid >> 6, lane = tid & 63, lm = lane & 15, g = lane >> 4;
  const int wr = wv >> 1, wc = wv & 1;      // 4 M-groups x 2 N-groups

  __shared__ __align__(16) char smem[98304];

  const f32x4 fzero = {0.f, 0.f, 0.f, 0.f};
  f32x4 acc[4][4];
#pragma unroll
  for (int i = 0; i < 4; ++i)
#pragma unroll
    for (int j = 0; j < 4; ++j) acc[i][j] = fzero;

  // staging: op = 16 KB = 1024 chunks (128 rows x 8); 2 loads/thread
  int srow[2], schk[2];
#pragma unroll
  for (int i = 0; i < 2; ++i){
    const int c = i * 512 + tid;
    srow[i] = c >> 3;
    schk[i] = (c & 7) ^ (srow[i] & 7);
  }
  const int sdst0 = ((0 * 512 + wv * 64) << 4);
  const int sdst1 = ((1 * 512 + wv * 64) << 4);

  // ops: 0 = A rows 0-127, 1 = A rows 128-255, 2 = B rows 0-127
  auto stg = [&](int kt, int op){
    if (kt < 64){
      char* dst = smem + (kt & 1) * 49152 + op * 16384;
      const bf16_t* base = (op < 2) ? A + (size_t)(m0 + (op << 7)) * HID
                                    : B + (size_t)n0 * HID;
      base += kt * 64;
      gload16(base + (size_t)srow[0] * HID + schk[0] * 8, dst + sdst0);
      gload16(base + (size_t)srow[1] * HID + schk[1] * 8, dst + sdst1);
    }
  };

  // fragment read constants (all frag rows == lm mod 8 -> same swizzle)
  const int koff0 = ((g)     ^ (lm & 7)) << 4;
  const int koff1 = ((4 + g) ^ (lm & 7)) << 4;
  const int abase = ((wr >> 1) << 14) + ((((wr & 1) << 6) + lm) << 7);
  const int bbase = 32768 + ((((wc << 6)) + lm) << 7);

  bf16x8 bfr[4][2];
  auto dsB = [&](int buf){
    const char* p = smem + buf * 49152 + bbase;
#pragma unroll
    for (int ni = 0; ni < 4; ++ni){
      bfr[ni][0] = *(const bf16x8*)(p + ni * 2048 + koff0);
      bfr[ni][1] = *(const bf16x8*)(p + ni * 2048 + koff1);
    }
  };

  // prologue: B(0), A(0), B(1); force B(0)+A(0), keep B(1) in flight
  stg(0, 2);
  stg(0, 0); stg(0, 1);
  stg(1, 2);
  asm volatile("s_waitcnt vmcnt(2)" ::: "memory");
  __builtin_amdgcn_s_barrier();

  for (int t = 0; t < 32; ++t){
    const int c0 = 2 * t, c1 = 2 * t + 1;
    const bool last = (t == 31);

#pragma unroll
    for (int half = 0; half < 2; ++half){
      const char* bufp = smem + half * 49152;
      bf16x8 afr[2][2];
      dsB(half);
#pragma unroll
      for (int mf = 0; mf < 2; ++mf){
        afr[mf][0] = *(const bf16x8*)(bufp + abase + mf * 2048 + koff0);
        afr[mf][1] = *(const bf16x8*)(bufp + abase + mf * 2048 + koff1);
      }
      if (half == 0){ stg(c1, 0); stg(c1, 1); }
      else          { stg(c0 + 2, 0); stg(c0 + 2, 1); }
      __builtin_amdgcn_s_barrier();
      asm volatile("s_waitcnt lgkmcnt(0)" ::: "memory");
      __builtin_amdgcn_s_setprio(1);
#pragma unroll
      for (int kk = 0; kk < 2; ++kk)
#pragma unroll
        for (int mf = 0; mf < 2; ++mf)
#pragma unroll
          for (int ni = 0; ni < 4; ++ni)
            acc[mf][ni] = __builtin_amdgcn_mfma_f32_16x16x32_bf16(afr[mf][kk], bfr[ni][kk], acc[mf][ni], 0, 0, 0);
      __builtin_amdgcn_s_setprio(0);
      __builtin_amdgcn_s_barrier();

#pragma unroll
      for (int mf = 0; mf < 2; ++mf){
        afr[mf][0] = *(const bf16x8*)(bufp + abase + (mf + 2) * 2048 + koff0);
        afr[mf][1] = *(const bf16x8*)(bufp + abase + (mf + 2) * 2048 + koff1);
      }
      if (half == 0) stg(c0 + 2, 2);
      else           stg(c1 + 2, 2);
      if (last) asm volatile("s_waitcnt vmcnt(0)" ::: "memory");
      else      asm volatile("s_waitcnt vmcnt(2)" ::: "memory");
      __builtin_amdgcn_s_barrier();
      asm volatile("s_waitcnt lgkmcnt(0)" ::: "memory");
      __builtin_amdgcn_s_setprio(1);
#pragma unroll
      for (int kk = 0; kk < 2; ++kk)
#pragma unroll
        for (int mf = 0; mf < 2; ++mf)
#pragma unroll
          for (int ni = 0; ni < 4; ++ni)
            acc[mf + 2][ni] = __builtin_amdgcn_mfma_f32_16x16x32_bf16(afr[mf][kk], bfr[ni][kk], acc[mf + 2][ni], 0, 0, 0);
      __builtin_amdgcn_s_setprio(0);
      __builtin_amdgcn_s_barrier();
    }
  }

  // epilogue
#pragma unroll
  for (int ni = 0; ni < 4; ++ni){
    const int col = n0 + wc * 64 + ni * 16 + lm;
#pragma unroll
    for (int mf = 0; mf < 4; ++mf)
#pragma unroll
      for (int r = 0; r < 4; ++r){
        const int trow = m0 + wr * 64 + mf * 16 + g * 4 + r;
        OF[(size_t)trow * HID + col] = acc[mf][ni][r];
      }
  }
}

// ---------------- flash attention: 32x32 MFMA, counted-vmcnt KV pipeline ----------------
// Q roped+scaled in-register (per-lane pair d <-> d+64 lives in qf[dc] / qf[dc+4]).
__global__ __launch_bounds__(256, 2) void attn2_k(
    const bf16_t* __restrict__ Q,
    const bf16_t* __restrict__ Kc,
    const bf16_t* __restrict__ VTc,
    const bf16_t* __restrict__ Kp,
    const bf16_t* __restrict__ VTp,
    bf16_t* __restrict__ Ctx,
    const int* __restrict__ plen_p,
    const int* __restrict__ pos)
{
  // XCD-chunked + complementary-qb balance remap (bijective)
  const int bid = blockIdx.x;          // 0..511
  const int xcd = bid & 7;
  const int k   = bid >> 3;            // 0..63
  const int ho  = k >> 4;              // 0..3
  const int qraw= k & 15;
  const int h   = (xcd << 2) | ho;
  const int qb  = (ho & 2) ? (15 - qraw) : qraw;

  const int tid = threadIdx.x;
  const int w = tid >> 6, lane = tid & 63, l31 = lane & 31, hi = lane >> 5;
  const int qw0 = qb * 128 + w * 32;
  const int qrow = qw0 + l31;
  const int plen = plen_p[0];
  const int npast = (plen + 63) >> 6;
  const int NT = npast + 2 * qb + 2;

  __shared__ __align__(16) char smem[65536 + 512];
  float* lred = (float*)(smem + 65536);   // per-wave 32-float broadcast slice

  // Q fragments from global; rope+scale in-register (consumes loads before stage(0))
  const bf16_t* qbase = Q + ((size_t)h * T_LEN + qrow) * DHEAD;
  bf16x8 qf[8];
#pragma unroll
  for (int dc = 0; dc < 8; ++dc)
    qf[dc] = *(const bf16x8*)(qbase + dc * 16 + 8 * hi);
  {
    const float ppos = (float)pos[qrow];
    const float qs = 0.08838834764831845f;   // 1/sqrt(128)
#pragma unroll
    for (int dc = 0; dc < 4; ++dc)
#pragma unroll
      for (int j = 0; j < 8; ++j){
        const int fi = dc * 16 + 8 * hi + j;               // freq index = d (< 64)
        const float invf = __expf(-(float)fi * 0.14391156605212898f);
        float sn, cs;
        sincosf(ppos * invf, &sn, &cs);
        const float a0 = (float)qf[dc][j], a1 = (float)qf[dc + 4][j];
        qf[dc][j]     = (bf16_t)((a0 * cs - a1 * sn) * qs);
        qf[dc + 4][j] = (bf16_t)((a1 * cs + a0 * sn) * qs);
      }
  }
  __builtin_amdgcn_sched_barrier(0);

  const f32x16 fz = {0.f,0.f,0.f,0.f,0.f,0.f,0.f,0.f,0.f,0.f,0.f,0.f,0.f,0.f,0.f,0.f};
  f32x16 o[4] = {fz, fz, fz, fz};
  float m = -1e30f, l = 0.f;

  auto stage = [&](int t, int buf){
    const bf16_t* kb; const bf16_t* vb;
    if (t < npast){
      const int s0 = t * 64;
      kb = Kp  + ((size_t)h * PAST_MAX + s0) * DHEAD;
      vb = VTp + (size_t)h * DHEAD * PAST_MAX + s0;
    } else {
      const int s0 = (t - npast) * 64;
      kb = Kc  + ((size_t)h * T_LEN + s0) * DHEAD;
      vb = VTc + (size_t)h * DHEAD * T_LEN + s0;
    }
    char* kl = smem + buf * 32768;
    char* vl = kl + 16384;
#pragma unroll
    for (int i = 0; i < 4; ++i){
      const int c = i * 256 + w * 64 + lane;
      const int krow = c >> 4, kcol = c & 15;          // K [64][128] bf16, 16 chunks/row
      gload16(kb + (size_t)krow * DHEAD + ((kcol ^ (krow & 7)) << 3), kl + (i * 256 + w * 64) * 16);
      const int vrow = c >> 3, vcol = c & 7;           // V^T [128][64] bf16, 8 chunks/row
      gload16(vb + (size_t)vrow * 2048 + ((vcol ^ (vrow & 7)) << 3), vl + (i * 256 + w * 64) * 16);
    }
  };

  stage(0, 0);
  __builtin_amdgcn_sched_barrier(0);

  for (int t = 0; t < NT; ++t){
    const int cur = t & 1;
    if (t + 1 < NT){
      stage(t + 1, cur ^ 1);
      asm volatile("s_waitcnt vmcnt(8)" ::: "memory");   // tile t landed; t+1 in flight
    } else {
      asm volatile("s_waitcnt vmcnt(0)" ::: "memory");
    }
    __builtin_amdgcn_sched_barrier(0);
    __builtin_amdgcn_s_barrier();
    __builtin_amdgcn_sched_barrier(0);

    const bool isc = (t >= npast);
    const int s0c = (t - npast) * 64;
    const bool active = !isc || (s0c <= qw0 + 31);

    if (active){
      char* kl = smem + cur * 32768;
      char* vl = kl + 16384;

      f32x16 sacc[2] = {fz, fz};
      __builtin_amdgcn_s_setprio(1);
#pragma unroll
      for (int kvh = 0; kvh < 2; ++kvh){
        const int krow = (kvh << 5) + l31;
        const int kbo = krow << 8;
        const int sw = (krow & 7) << 4;
#pragma unroll
        for (int dc = 0; dc < 8; ++dc){
          const bf16x8 kf = *(const bf16x8*)(kl + kbo + ((dc * 32 + 16 * hi) ^ sw));
          sacc[kvh] = __builtin_amdgcn_mfma_f32_32x32x16_bf16(kf, qf[dc], sacc[kvh], 0, 0, 0);
        }
      }
      __builtin_amdgcn_s_setprio(0);

      // mask-hoist: only diagonal/boundary tiles pay the per-element mask chain
      const bool mcur  = isc && (s0c + 63 > qw0);
      const bool mpast = !isc && ((t + 1) * 64 > plen);
      float pv[2][16];
      float pm = -1e30f;
      if (mcur | mpast){
#pragma unroll
        for (int kvh = 0; kvh < 2; ++kvh)
#pragma unroll
          for (int r = 0; r < 16; ++r){
            float x = sacc[kvh][r];
            const int kvoff = (kvh << 5) + (r & 3) + 8 * (r >> 2) + 4 * hi;
            if (mcur  && (s0c + kvoff >  qrow)) x = -1e30f;
            if (mpast && (t * 64 + kvoff >= plen)) x = -1e30f;
            pv[kvh][r] = x;
            pm = fmaxf(pm, x);
          }
      } else {
#pragma unroll
        for (int kvh = 0; kvh < 2; ++kvh)
#pragma unroll
          for (int r = 0; r < 16; ++r){
            pv[kvh][r] = sacc[kvh][r];
            pm = fmaxf(pm, sacc[kvh][r]);
          }
      }
      pm = fmaxf(pm, __shfl_xor(pm, 32));

      // defer-max: rescale only when max grows past threshold
      if (!__all(pm - m <= 8.f)){
        const float mn = fmaxf(m, pm);
        const float corr = __expf(m - mn);
        m = mn;
        l *= corr;
        if (hi == 0) lred[(w << 5) + l31] = corr;
        asm volatile("s_waitcnt lgkmcnt(0)" ::: "memory");
#pragma unroll
        for (int r = 0; r < 16; ++r){
          const float cc = lred[(w << 5) + (r & 3) + 8 * (r >> 2) + 4 * hi];
#pragma unroll
          for (int nb = 0; nb < 4; ++nb) o[nb][r] *= cc;
        }
      }

      float sum = 0.f;
#pragma unroll
      for (int kvh = 0; kvh < 2; ++kvh)
#pragma unroll
        for (int r = 0; r < 16; ++r){
          const float pe = __expf(pv[kvh][r] - m);
          pv[kvh][r] = pe;
          sum += pe;
        }
      sum += __shfl_xor(sum, 32);
      l += sum;

      // pack own 32 P to 16 words; partner-exchange 8 words -> PV A-frags
      unsigned wds[2][8];
#pragma unroll
      for (int kvh = 0; kvh < 2; ++kvh)
#pragma unroll
        for (int i = 0; i < 8; ++i)
          wds[kvh][i] = pack_bf16(pv[kvh][2 * i], pv[kvh][2 * i + 1]);

      bf16x8 pf[4];
#pragma unroll
      for (int ks = 0; ks < 4; ++ks){
        const int s = ks & 1, kvh = ks >> 1;
        const unsigned a0 = hi ? wds[kvh][4 * s]     : wds[kvh][4 * s + 2];
        const unsigned a1 = hi ? wds[kvh][4 * s + 1] : wds[kvh][4 * s + 3];
        const unsigned z0 = (unsigned)__shfl_xor((int)a0, 32);
        const unsigned z1 = (unsigned)__shfl_xor((int)a1, 32);
        u32x4 fw;
        fw[0] = hi ? z0 : wds[kvh][4 * s];
        fw[1] = hi ? z1 : wds[kvh][4 * s + 1];
        fw[2] = hi ? wds[kvh][4 * s + 2] : z0;
        fw[3] = hi ? wds[kvh][4 * s + 3] : z1;
        pf[ks] = __builtin_bit_cast(bf16x8, fw);
      }

      // PV: O[q][dv] += P·V, V^T frags from LDS
      __builtin_amdgcn_s_setprio(1);
#pragma unroll
      for (int ks = 0; ks < 4; ++ks)
#pragma unroll
        for (int nb = 0; nb < 4; ++nb){
          const int vrow = (nb << 5) + l31;
          const bf16x8 vf = *(const bf16x8*)(vl + (vrow << 7) + ((ks * 32 + 16 * hi) ^ ((vrow & 7) << 4)));
          o[nb] = __builtin_amdgcn_mfma_f32_32x32x16_bf16(pf[ks], vf, o[nb], 0, 0, 0);
        }
      __builtin_amdgcn_s_setprio(0);
    }
    __builtin_amdgcn_sched_barrier(0);
    __builtin_amdgcn_s_barrier();       // WAR release: buf cur free for t+2's stage
  }

  // epilogue: O / l -> Ctx [T][HID]
  if (hi == 0) lred[(w << 5) + l31] = l;
  asm volatile("s_waitcnt lgkmcnt(0)" ::: "memory");
#pragma unroll
  for (int r = 0; r < 16; ++r){
    const int cr = (r & 3) + 8 * (r >> 2) + 4 * hi;
    const float li = 1.f / lred[(w << 5) + cr];
    const int trow = qw0 + cr;
    bf16_t* cb = Ctx + (size_t)trow * HID + h * DHEAD + l31;
#pragma unroll
    for (int nb = 0; nb < 4; ++nb)
      cb[nb << 5] = (bf16_t)(o[nb][r] * li);
  }
}

// ---------------- launcher ----------------
extern "C" void kernel_launch(void* const* d_in, const int* in_sizes, int n_in,
                              void* d_out, int out_size, void* d_ws, size_t ws_size,
                              hipStream_t stream)
{
  const float* X   = (const float*)d_in[0];
  const float* Wq  = (const float*)d_in[2];
  const float* Wk  = (const float*)d_in[3];
  const float* Wv  = (const float*)d_in[4];
  const float* Wo  = (const float*)d_in[5];
  const float* PKi = (const float*)d_in[6];
  const float* PVi = (const float*)d_in[7];
  const int* POS   = (const int*)d_in[8];
  const int* PLEN  = (const int*)d_in[9];
  float* OUT = (float*)d_out;

  char* ws = (char*)d_ws;
  const size_t SZ_XB  = (size_t)T_LEN * HID * 2;             // 16 MiB
  const size_t SZ_W   = (size_t)HID * HID * 2;               // 32 MiB
  const size_t SZ_HTD = (size_t)NHEAD * T_LEN * DHEAD * 2;   // 16 MiB

  bf16_t* XB  = (bf16_t*)(ws);
  bf16_t* WT0 = (bf16_t*)(ws + SZ_XB);
  bf16_t* WT1 = (bf16_t*)(ws + SZ_XB + SZ_W);
  bf16_t* WT2 = (bf16_t*)(ws + SZ_XB + 2 * SZ_W);
  char* p = ws + SZ_XB + 3 * SZ_W;
  bf16_t* QB   = (bf16_t*)p; p += SZ_HTD;
  bf16_t* KB   = (bf16_t*)p; p += SZ_HTD;
  bf16_t* VTB  = (bf16_t*)p; p += SZ_HTD;
  bf16_t* KPB  = (bf16_t*)p; p += SZ_HTD;
  bf16_t* VPTB = (bf16_t*)p; p += SZ_HTD;
  bf16_t* CTX  = (bf16_t*)p; p += SZ_HTD;
  bf16_t* WOT  = QB;   // reuse QB+KB (32 MiB contiguous) after attention

  dim3 blk256(256);
  dim3 blk512(512);
  cvt2_k<<<16384, blk256, 0, stream>>>(X, XB, PKi, KPB, T_LEN * HID / 4);
  transpose3_k<<<dim3(64,64,3), blk256, 0, stream>>>(Wq, Wk, Wv, WT0, WT1, WT2);
  transpose2_k<<<dim3(32,2,32), blk256, 0, stream>>>(PVi, VPTB, PAST_MAX, DHEAD);

  gemmqkv8p_k<<<384, blk512, 0, stream>>>(XB, WT0, WT1, WT2, QB, KB, VTB, 48);
  ropek_k<<<16384, blk256, 0, stream>>>(KB, POS);
  attn2_k<<<512, blk256, 0, stream>>>(QB, KB, VTB, KPB, VPTB, CTX, PLEN, POS);

  transpose2_k<<<dim3(64,64,1), blk256, 0, stream>>>(Wo, WOT, HID, HID);
  gemm4p_k<<<256, blk512, 0, stream>>>(CTX, WOT, OUT, 32);
}

// Round 4
// 596.530 us; speedup vs baseline: 1.0130x; 1.0130x over previous
//
#include <hip/hip_runtime.h>
#include <cstdint>
#include <cstddef>

#define T_LEN 2048
#define PAST_MAX 2048
#define HID 4096
#define NHEAD 32
#define DHEAD 128

typedef __bf16 bf16_t;
typedef __bf16 bf16x4 __attribute__((ext_vector_type(4)));
typedef __bf16 bf16x8 __attribute__((ext_vector_type(8)));
typedef float  f32x4  __attribute__((ext_vector_type(4)));
typedef float  f32x16 __attribute__((ext_vector_type(16)));
typedef unsigned int u32x4 __attribute__((ext_vector_type(4)));

__device__ __forceinline__ void gload16(const void* g, void* l){
  __builtin_amdgcn_global_load_lds((const __attribute__((address_space(1))) void*)g,
                                   (__attribute__((address_space(3))) void*)l,
                                   16, 0, 0);
}

__device__ __forceinline__ unsigned pack_bf16(float a, float b){
  const unsigned ua = __builtin_bit_cast(unsigned short, (bf16_t)a);
  const unsigned ub = __builtin_bit_cast(unsigned short, (bf16_t)b);
  return ua | (ub << 16);
}

// ---------------- fused f32 -> bf16 for X and past_k ----------------
__global__ void cvt2_k(const float* __restrict__ a, bf16_t* __restrict__ ao,
                       const float* __restrict__ b, bf16_t* __restrict__ bo, int n4){
  int i = blockIdx.x * 256 + threadIdx.x;
  if (i < n4){
    const float4 v = ((const float4*)a)[i];
    bf16x4 o = { (bf16_t)v.x, (bf16_t)v.y, (bf16_t)v.z, (bf16_t)v.w };
    ((bf16x4*)ao)[i] = o;
  } else {
    i -= n4;
    const float4 v = ((const float4*)b)[i];
    bf16x4 o = { (bf16_t)v.x, (bf16_t)v.y, (bf16_t)v.z, (bf16_t)v.w };
    ((bf16x4*)bo)[i] = o;
  }
}

// ---------------- f32 [B][R][C] -> bf16 [B][C][R], 64x64 tiles ----------------
__global__ __launch_bounds__(256) void transpose2_k(const float* __restrict__ in,
                                                    bf16_t* __restrict__ out, int R, int C){
  __shared__ float tile[64][65];
  const int r0 = blockIdx.x << 6, c0 = blockIdx.y << 6;
  const size_t bo = (size_t)blockIdx.z * (size_t)R * (size_t)C;
  const int tx = threadIdx.x & 15, ty = threadIdx.x >> 4;
#pragma unroll
  for (int k = 0; k < 4; ++k){
    const float4 v = *(const float4*)(in + bo + (size_t)(r0 + ty + 16*k) * C + c0 + tx*4);
    float* tp = &tile[ty + 16*k][tx*4];
    tp[0] = v.x; tp[1] = v.y; tp[2] = v.z; tp[3] = v.w;
  }
  __syncthreads();
  const int rr0 = (threadIdx.x & 7) * 8;
  const int ccb = threadIdx.x >> 3;     // 0..31
#pragma unroll
  for (int k = 0; k < 2; ++k){
    const int cc = ccb + 32*k;
    bf16x8 o;
#pragma unroll
    for (int j = 0; j < 8; ++j) o[j] = (bf16_t)tile[rr0 + j][cc];
    *(bf16x8*)(out + bo + (size_t)(c0 + cc) * R + r0 + rr0) = o;
  }
}

// ---------------- fused transpose of Wq/Wk/Wv (z selects) ----------------
__global__ __launch_bounds__(256) void transpose3_k(
    const float* __restrict__ s0, const float* __restrict__ s1, const float* __restrict__ s2,
    bf16_t* __restrict__ d0, bf16_t* __restrict__ d1, bf16_t* __restrict__ d2){
  __shared__ float tile[64][65];
  const float* in = (blockIdx.z == 0) ? s0 : (blockIdx.z == 1) ? s1 : s2;
  bf16_t* out = (blockIdx.z == 0) ? d0 : (blockIdx.z == 1) ? d1 : d2;
  const int r0 = blockIdx.x << 6, c0 = blockIdx.y << 6;
  const int tx = threadIdx.x & 15, ty = threadIdx.x >> 4;
#pragma unroll
  for (int k = 0; k < 4; ++k){
    const float4 v = *(const float4*)(in + (size_t)(r0 + ty + 16*k) * HID + c0 + tx*4);
    float* tp = &tile[ty + 16*k][tx*4];
    tp[0] = v.x; tp[1] = v.y; tp[2] = v.z; tp[3] = v.w;
  }
  __syncthreads();
  const int rr0 = (threadIdx.x & 7) * 8;
  const int ccb = threadIdx.x >> 3;
#pragma unroll
  for (int k = 0; k < 2; ++k){
    const int cc = ccb + 32*k;
    bf16x8 o;
#pragma unroll
    for (int j = 0; j < 8; ++j) o[j] = (bf16_t)tile[rr0 + j][cc];
    *(bf16x8*)(out + (size_t)(c0 + cc) * HID + r0 + rr0) = o;
  }
}

// ---------------- RoPE in place on K only (Q roped in-register inside attn) ------------
__global__ void ropek_k(bf16_t* __restrict__ K, const int* __restrict__ pos){
  const int idx = blockIdx.x * 256 + threadIdx.x;     // 32*2048*64 total
  const int i = idx & 63;
  const int t = (idx >> 6) & (T_LEN - 1);
  const int h = idx >> 17;
  const size_t base = ((size_t)h * T_LEN + t) * DHEAD;
  const float p = (float)pos[t];
  const float inv = __expf(-(float)i * 0.14391156605212898f);  // ln(10000)/64
  const float ang = p * inv;
  float sn, cs;
  sincosf(ang, &sn, &cs);
  const float b0 = (float)K[base + i], b1 = (float)K[base + i + 64];
  K[base + i]      = (bf16_t)(b0 * cs - b1 * sn);
  K[base + i + 64] = (bf16_t)(b1 * cs + b0 * sn);
}

// ------------- QKV: 256x128 BK=32, ring-4 LDS + REGISTER-double-buffered frags --------
// R0-R3 post-mortem: all 4 schedules tie at 32-37% MfmaUtil because fragment ds_reads are
// issued right before their consuming MFMA cluster (barrier+lgkm drain between) -> ~400+cy
// exposed LDS latency per K-tile on top of the ~1000cy LDS-BW floor. Fix: read tile kt+1's
// fragments into the ALTERNATE register set during tile kt's MFMA; the compiler's lgkm
// drain before MFMA(kt+1) then waits on ~600cy-old reads -> ~0 exposed. One phase and ONE
// barrier per K-tile. No explicit lgkmcnt(0) (WAR: tile kt-1's reads drain before
// MFMA(kt-1), which precedes iter kt's barrier; stg(kt+3) lands after that barrier).
// Ring-4 x 24KB = 96KB; stg lead = 2 tiles; steady-state vmcnt(3) (stg(kt+2) in flight).
// Layout/swizzle constants identical to R0's proven gemm2b (0 bank conflicts measured).
// Grid 768 = 3 exact generations at 1 block/CU -> no tail imbalance.
__global__ __launch_bounds__(512, 1) void gemmqkv_rr_k(
    const bf16_t* __restrict__ A,
    const bf16_t* __restrict__ B0, const bf16_t* __restrict__ B1, const bf16_t* __restrict__ B2,
    bf16_t* __restrict__ OQ, bf16_t* __restrict__ OK2, bf16_t* __restrict__ OVT, int cpx)
{
  const int bid = blockIdx.x;
  const int wg  = (bid & 7) * cpx + (bid >> 3);   // cpx = 96
  const int mt  = wg & 7;
  const int rest = wg >> 3;
  const int z   = rest >> 5;
  const int nt  = rest & 31;
  const int m0  = mt << 8;
  const int n0  = nt << 7;
  const bf16_t* __restrict__ B = (z == 0) ? B0 : (z == 1) ? B1 : B2;

  const int tid = threadIdx.x;
  const int wv = tid >> 6, lane = tid & 63, lm = lane & 15, g = lane >> 4;
  const int wr = wv >> 1, wc = wv & 1;      // 4 M-groups x 2 N-groups (wave tile 64x64)

  __shared__ __align__(16) char smem[98304];   // ring: 4 slots x (A 16K + B 8K)

  const f32x4 fzero = {0.f, 0.f, 0.f, 0.f};
  f32x4 acc[4][4];
#pragma unroll
  for (int i = 0; i < 4; ++i)
#pragma unroll
    for (int j = 0; j < 4; ++j) acc[i][j] = fzero;

  // staging offsets (R0 exact: inverse-swizzled sources, linear LDS dst; rows = 64 B)
  size_t aoff[2], boff;
#pragma unroll
  for (int i = 0; i < 2; ++i){
    const int c = i * 512 + tid;
    const int row = c >> 2, gr = c & 3;
    const int srcg = gr ^ ((row >> 1) & 3);
    aoff[i] = (size_t)(m0 + row) * HID + srcg * 8;
  }
  {
    const int row = tid >> 2, gr = tid & 3;
    const int srcg = gr ^ ((row >> 1) & 3);
    boff = (size_t)(n0 + row) * HID + srcg * 8;
  }
  const int adst0 = ((0 * 512 + wv * 64) << 4);
  const int adst1 = ((1 * 512 + wv * 64) << 4);
  const int bdst  = ((wv * 64) << 4);

  auto stg = [&](int kt){
    if (kt < 128){
      char* ab = smem + (kt & 3) * 24576;
      char* bb = ab + 16384;
      const bf16_t* Ak = A + kt * 32;
      const bf16_t* Bk = B + kt * 32;
      gload16(Ak + aoff[0], ab + adst0);
      gload16(Ak + aoff[1], ab + adst1);
      gload16(Bk + boff,    bb + bdst);
    }
  };

  // fragment read constants (R0 exact): swizzle lane-constant across mf/ni
  const int ksw = ((g ^ ((lm >> 1) & 3)) << 4);
  const int arow = (wr * 64 + lm) * 64;
  const int brow = (wc * 64 + lm) * 64;

  auto rd = [&](int kt, bf16x8 (&af)[4], bf16x8 (&bfv)[4]){
    const char* ab = smem + (kt & 3) * 24576;
    const char* bb = ab + 16384;
#pragma unroll
    for (int mf = 0; mf < 4; ++mf)
      af[mf] = *(const bf16x8*)(ab + arow + mf * 1024 + ksw);
#pragma unroll
    for (int ni = 0; ni < 4; ++ni)
      bfv[ni] = *(const bf16x8*)(bb + brow + ni * 1024 + ksw);
  };

  auto mm = [&](bf16x8 (&af)[4], bf16x8 (&bfv)[4]){
    __builtin_amdgcn_s_setprio(1);
#pragma unroll
    for (int mf = 0; mf < 4; ++mf)
#pragma unroll
      for (int ni = 0; ni < 4; ++ni)
        acc[mf][ni] = __builtin_amdgcn_mfma_f32_16x16x32_bf16(af[mf], bfv[ni], acc[mf][ni], 0, 0, 0);
    __builtin_amdgcn_s_setprio(0);
  };

  // prologue: tiles 0,1,2 staged; tile 0 published; tile-0 frags in regs A
  bf16x8 afA[4], bfA[4], afB[4], bfB[4];
  stg(0); stg(1); stg(2);
  asm volatile("s_waitcnt vmcnt(6)" ::: "memory");
  __builtin_amdgcn_s_barrier();
  rd(0, afA, bfA);

  for (int i = 0; i < 64; ++i){
    const int e = 2 * i;
    // ---- even tile e: publish e+1, prefetch its frags, compute tile e ----
    if (e <= 125) asm volatile("s_waitcnt vmcnt(3)" ::: "memory");
    else          asm volatile("s_waitcnt vmcnt(0)" ::: "memory");
    __builtin_amdgcn_s_barrier();
    rd(e + 1, afB, bfB);                 // e+1 <= 127 always
    stg(e + 3);
    __builtin_amdgcn_sched_barrier(0);
    mm(afA, bfA);

    const int o = e + 1;
    // ---- odd tile o ----
    if (o <= 125) asm volatile("s_waitcnt vmcnt(3)" ::: "memory");
    else          asm volatile("s_waitcnt vmcnt(0)" ::: "memory");
    __builtin_amdgcn_s_barrier();
    if (o < 127) rd(o + 1, afA, bfA);
    stg(o + 3);
    __builtin_amdgcn_sched_barrier(0);
    mm(afB, bfB);
  }

  // epilogue: 3-way layout select (Q/K [H][T][D], V^T [H][D][T])
#pragma unroll
  for (int ni = 0; ni < 4; ++ni){
    const int col = n0 + wc * 64 + ni * 16 + lm;
    const int hh = col >> 7, dd = col & 127;
#pragma unroll
    for (int mf = 0; mf < 4; ++mf)
#pragma unroll
      for (int r = 0; r < 4; ++r){
        const int trow = m0 + wr * 64 + mf * 16 + g * 4 + r;
        const bf16_t v = (bf16_t)acc[mf][ni][r];
        if (z == 2)      OVT[((size_t)hh * DHEAD + dd) * T_LEN + trow] = v;
        else if (z == 1) OK2[((size_t)hh * T_LEN + trow) * DHEAD + dd] = v;
        else             OQ [((size_t)hh * T_LEN + trow) * DHEAD + dd] = v;
      }
  }
}

// ------------- out-proj: same ring-4 reg-dbuf template, f32 output, grid 256 ----------
__global__ __launch_bounds__(512, 1) void gemmop_rr_k(
    const bf16_t* __restrict__ A, const bf16_t* __restrict__ B,
    float* __restrict__ OF, int cpx)
{
  const int bid = blockIdx.x;
  const int wg  = (bid & 7) * cpx + (bid >> 3);   // cpx = 32
  const int mt  = wg & 7;
  const int nt  = wg >> 3;
  const int m0  = mt << 8;
  const int n0  = nt << 7;

  const int tid = threadIdx.x;
  const int wv = tid >> 6, lane = tid & 63, lm = lane & 15, g = lane >> 4;
  const int wr = wv >> 1, wc = wv & 1;

  __shared__ __align__(16) char smem[98304];

  const f32x4 fzero = {0.f, 0.f, 0.f, 0.f};
  f32x4 acc[4][4];
#pragma unroll
  for (int i = 0; i < 4; ++i)
#pragma unroll
    for (int j = 0; j < 4; ++j) acc[i][j] = fzero;

  size_t aoff[2], boff;
#pragma unroll
  for (int i = 0; i < 2; ++i){
    const int c = i * 512 + tid;
    const int row = c >> 2, gr = c & 3;
    const int srcg = gr ^ ((row >> 1) & 3);
    aoff[i] = (size_t)(m0 + row) * HID + srcg * 8;
  }
  {
    const int row = tid >> 2, gr = tid & 3;
    const int srcg = gr ^ ((row >> 1) & 3);
    boff = (size_t)(n0 + row) * HID + srcg * 8;
  }
  const int adst0 = ((0 * 512 + wv * 64) << 4);
  const int adst1 = ((1 * 512 + wv * 64) << 4);
  const int bdst  = ((wv * 64) << 4);

  auto stg = [&](int kt){
    if (kt < 128){
      char* ab = smem + (kt & 3) * 24576;
      char* bb = ab + 16384;
      const bf16_t* Ak = A + kt * 32;
      const bf16_t* Bk = B + kt * 32;
      gload16(Ak + aoff[0], ab + adst0);
      gload16(Ak + aoff[1], ab + adst1);
      gload16(Bk + boff,    bb + bdst);
    }
  };

  const int ksw = ((g ^ ((lm >> 1) & 3)) << 4);
  const int arow = (wr * 64 + lm) * 64;
  const int brow = (wc * 64 + lm) * 64;

  auto rd = [&](int kt, bf16x8 (&af)[4], bf16x8 (&bfv)[4]){
    const char* ab = smem + (kt & 3) * 24576;
    const char* bb = ab + 16384;
#pragma unroll
    for (int mf = 0; mf < 4; ++mf)
      af[mf] = *(const bf16x8*)(ab + arow + mf * 1024 + ksw);
#pragma unroll
    for (int ni = 0; ni < 4; ++ni)
      bfv[ni] = *(const bf16x8*)(bb + brow + ni * 1024 + ksw);
  };

  auto mm = [&](bf16x8 (&af)[4], bf16x8 (&bfv)[4]){
    __builtin_amdgcn_s_setprio(1);
#pragma unroll
    for (int mf = 0; mf < 4; ++mf)
#pragma unroll
      for (int ni = 0; ni < 4; ++ni)
        acc[mf][ni] = __builtin_amdgcn_mfma_f32_16x16x32_bf16(af[mf], bfv[ni], acc[mf][ni], 0, 0, 0);
    __builtin_amdgcn_s_setprio(0);
  };

  bf16x8 afA[4], bfA[4], afB[4], bfB[4];
  stg(0); stg(1); stg(2);
  asm volatile("s_waitcnt vmcnt(6)" ::: "memory");
  __builtin_amdgcn_s_barrier();
  rd(0, afA, bfA);

  for (int i = 0; i < 64; ++i){
    const int e = 2 * i;
    if (e <= 125) asm volatile("s_waitcnt vmcnt(3)" ::: "memory");
    else          asm volatile("s_waitcnt vmcnt(0)" ::: "memory");
    __builtin_amdgcn_s_barrier();
    rd(e + 1, afB, bfB);
    stg(e + 3);
    __builtin_amdgcn_sched_barrier(0);
    mm(afA, bfA);

    const int o = e + 1;
    if (o <= 125) asm volatile("s_waitcnt vmcnt(3)" ::: "memory");
    else          asm volatile("s_waitcnt vmcnt(0)" ::: "memory");
    __builtin_amdgcn_s_barrier();
    if (o < 127) rd(o + 1, afA, bfA);
    stg(o + 3);
    __builtin_amdgcn_sched_barrier(0);
    mm(afB, bfB);
  }

  // epilogue
#pragma unroll
  for (int ni = 0; ni < 4; ++ni){
    const int col = n0 + wc * 64 + ni * 16 + lm;
#pragma unroll
    for (int mf = 0; mf < 4; ++mf)
#pragma unroll
      for (int r = 0; r < 4; ++r){
        const int trow = m0 + wr * 64 + mf * 16 + g * 4 + r;
        OF[(size_t)trow * HID + col] = acc[mf][ni][r];
      }
  }
}

// ---------------- flash attention: 32x32 MFMA, counted-vmcnt KV pipeline ----------------
// Q roped+scaled in-register (per-lane pair d <-> d+64 lives in qf[dc] / qf[dc+4]).
__global__ __launch_bounds__(256, 2) void attn2_k(
    const bf16_t* __restrict__ Q,
    const bf16_t* __restrict__ Kc,
    const bf16_t* __restrict__ VTc,
    const bf16_t* __restrict__ Kp,
    const bf16_t* __restrict__ VTp,
    bf16_t* __restrict__ Ctx,
    const int* __restrict__ plen_p,
    const int* __restrict__ pos)
{
  // XCD-chunked + complementary-qb balance remap (bijective)
  const int bid = blockIdx.x;          // 0..511
  const int xcd = bid & 7;
  const int k   = bid >> 3;            // 0..63
  const int ho  = k >> 4;              // 0..3
  const int qraw= k & 15;
  const int h   = (xcd << 2) | ho;
  const int qb  = (ho & 2) ? (15 - qraw) : qraw;

  const int tid = threadIdx.x;
  const int w = tid >> 6, lane = tid & 63, l31 = lane & 31, hi = lane >> 5;
  const int qw0 = qb * 128 + w * 32;
  const int qrow = qw0 + l31;
  const int plen = plen_p[0];
  const int npast = (plen + 63) >> 6;
  const int NT = npast + 2 * qb + 2;

  __shared__ __align__(16) char smem[65536 + 512];
  float* lred = (float*)(smem + 65536);   // per-wave 32-float broadcast slice

  // Q fragments from global; rope+scale in-register (consumes loads before stage(0))
  const bf16_t* qbase = Q + ((size_t)h * T_LEN + qrow) * DHEAD;
  bf16x8 qf[8];
#pragma unroll
  for (int dc = 0; dc < 8; ++dc)
    qf[dc] = *(const bf16x8*)(qbase + dc * 16 + 8 * hi);
  {
    const float ppos = (float)pos[qrow];
    const float qs = 0.08838834764831845f;   // 1/sqrt(128)
#pragma unroll
    for (int dc = 0; dc < 4; ++dc)
#pragma unroll
      for (int j = 0; j < 8; ++j){
        const int fi = dc * 16 + 8 * hi + j;               // freq index = d (< 64)
        const float invf = __expf(-(float)fi * 0.14391156605212898f);
        float sn, cs;
        sincosf(ppos * invf, &sn, &cs);
        const float a0 = (float)qf[dc][j], a1 = (float)qf[dc + 4][j];
        qf[dc][j]     = (bf16_t)((a0 * cs - a1 * sn) * qs);
        qf[dc + 4][j] = (bf16_t)((a1 * cs + a0 * sn) * qs);
      }
  }
  __builtin_amdgcn_sched_barrier(0);

  const f32x16 fz = {0.f,0.f,0.f,0.f,0.f,0.f,0.f,0.f,0.f,0.f,0.f,0.f,0.f,0.f,0.f,0.f};
  f32x16 o[4] = {fz, fz, fz, fz};
  float m = -1e30f, l = 0.f;

  auto stage = [&](int t, int buf){
    const bf16_t* kb; const bf16_t* vb;
    if (t < npast){
      const int s0 = t * 64;
      kb = Kp  + ((size_t)h * PAST_MAX + s0) * DHEAD;
      vb = VTp + (size_t)h * DHEAD * PAST_MAX + s0;
    } else {
      const int s0 = (t - npast) * 64;
      kb = Kc  + ((size_t)h * T_LEN + s0) * DHEAD;
      vb = VTc + (size_t)h * DHEAD * T_LEN + s0;
    }
    char* kl = smem + buf * 32768;
    char* vl = kl + 16384;
#pragma unroll
    for (int i = 0; i < 4; ++i){
      const int c = i * 256 + w * 64 + lane;
      const int krow = c >> 4, kcol = c & 15;          // K [64][128] bf16, 16 chunks/row
      gload16(kb + (size_t)krow * DHEAD + ((kcol ^ (krow & 7)) << 3), kl + (i * 256 + w * 64) * 16);
      const int vrow = c >> 3, vcol = c & 7;           // V^T [128][64] bf16, 8 chunks/row
      gload16(vb + (size_t)vrow * 2048 + ((vcol ^ (vrow & 7)) << 3), vl + (i * 256 + w * 64) * 16);
    }
  };

  stage(0, 0);
  __builtin_amdgcn_sched_barrier(0);

  for (int t = 0; t < NT; ++t){
    const int cur = t & 1;
    if (t + 1 < NT){
      stage(t + 1, cur ^ 1);
      asm volatile("s_waitcnt vmcnt(8)" ::: "memory");   // tile t landed; t+1 in flight
    } else {
      asm volatile("s_waitcnt vmcnt(0)" ::: "memory");
    }
    __builtin_amdgcn_sched_barrier(0);
    __builtin_amdgcn_s_barrier();
    __builtin_amdgcn_sched_barrier(0);

    const bool isc = (t >= npast);
    const int s0c = (t - npast) * 64;
    const bool active = !isc || (s0c <= qw0 + 31);

    if (active){
      char* kl = smem + cur * 32768;
      char* vl = kl + 16384;

      f32x16 sacc[2] = {fz, fz};
      __builtin_amdgcn_s_setprio(1);
#pragma unroll
      for (int kvh = 0; kvh < 2; ++kvh){
        const int krow = (kvh << 5) + l31;
        const int kbo = krow << 8;
        const int sw = (krow & 7) << 4;
#pragma unroll
        for (int dc = 0; dc < 8; ++dc){
          const bf16x8 kf = *(const bf16x8*)(kl + kbo + ((dc * 32 + 16 * hi) ^ sw));
          sacc[kvh] = __builtin_amdgcn_mfma_f32_32x32x16_bf16(kf, qf[dc], sacc[kvh], 0, 0, 0);
        }
      }
      __builtin_amdgcn_s_setprio(0);

      // mask-hoist: only diagonal/boundary tiles pay the per-element mask chain
      const bool mcur  = isc && (s0c + 63 > qw0);
      const bool mpast = !isc && ((t + 1) * 64 > plen);
      float pv[2][16];
      float pm = -1e30f;
      if (mcur | mpast){
#pragma unroll
        for (int kvh = 0; kvh < 2; ++kvh)
#pragma unroll
          for (int r = 0; r < 16; ++r){
            float x = sacc[kvh][r];
            const int kvoff = (kvh << 5) + (r & 3) + 8 * (r >> 2) + 4 * hi;
            if (mcur  && (s0c + kvoff >  qrow)) x = -1e30f;
            if (mpast && (t * 64 + kvoff >= plen)) x = -1e30f;
            pv[kvh][r] = x;
            pm = fmaxf(pm, x);
          }
      } else {
#pragma unroll
        for (int kvh = 0; kvh < 2; ++kvh)
#pragma unroll
          for (int r = 0; r < 16; ++r){
            pv[kvh][r] = sacc[kvh][r];
            pm = fmaxf(pm, sacc[kvh][r]);
          }
      }
      pm = fmaxf(pm, __shfl_xor(pm, 32));

      // defer-max: rescale only when max grows past threshold
      if (!__all(pm - m <= 8.f)){
        const float mn = fmaxf(m, pm);
        const float corr = __expf(m - mn);
        m = mn;
        l *= corr;
        if (hi == 0) lred[(w << 5) + l31] = corr;
        asm volatile("s_waitcnt lgkmcnt(0)" ::: "memory");
#pragma unroll
        for (int r = 0; r < 16; ++r){
          const float cc = lred[(w << 5) + (r & 3) + 8 * (r >> 2) + 4 * hi];
#pragma unroll
          for (int nb = 0; nb < 4; ++nb) o[nb][r] *= cc;
        }
      }

      float sum = 0.f;
#pragma unroll
      for (int kvh = 0; kvh < 2; ++kvh)
#pragma unroll
        for (int r = 0; r < 16; ++r){
          const float pe = __expf(pv[kvh][r] - m);
          pv[kvh][r] = pe;
          sum += pe;
        }
      sum += __shfl_xor(sum, 32);
      l += sum;

      // pack own 32 P to 16 words; partner-exchange 8 words -> PV A-frags
      unsigned wds[2][8];
#pragma unroll
      for (int kvh = 0; kvh < 2; ++kvh)
#pragma unroll
        for (int i = 0; i < 8; ++i)
          wds[kvh][i] = pack_bf16(pv[kvh][2 * i], pv[kvh][2 * i + 1]);

      bf16x8 pf[4];
#pragma unroll
      for (int ks = 0; ks < 4; ++ks){
        const int s = ks & 1, kvh = ks >> 1;
        const unsigned a0 = hi ? wds[kvh][4 * s]     : wds[kvh][4 * s + 2];
        const unsigned a1 = hi ? wds[kvh][4 * s + 1] : wds[kvh][4 * s + 3];
        const unsigned z0 = (unsigned)__shfl_xor((int)a0, 32);
        const unsigned z1 = (unsigned)__shfl_xor((int)a1, 32);
        u32x4 fw;
        fw[0] = hi ? z0 : wds[kvh][4 * s];
        fw[1] = hi ? z1 : wds[kvh][4 * s + 1];
        fw[2] = hi ? wds[kvh][4 * s + 2] : z0;
        fw[3] = hi ? wds[kvh][4 * s + 3] : z1;
        pf[ks] = __builtin_bit_cast(bf16x8, fw);
      }

      // PV: O[q][dv] += P·V, V^T frags from LDS
      __builtin_amdgcn_s_setprio(1);
#pragma unroll
      for (int ks = 0; ks < 4; ++ks)
#pragma unroll
        for (int nb = 0; nb < 4; ++nb){
          const int vrow = (nb << 5) + l31;
          const bf16x8 vf = *(const bf16x8*)(vl + (vrow << 7) + ((ks * 32 + 16 * hi) ^ ((vrow & 7) << 4)));
          o[nb] = __builtin_amdgcn_mfma_f32_32x32x16_bf16(pf[ks], vf, o[nb], 0, 0, 0);
        }
      __builtin_amdgcn_s_setprio(0);
    }
    __builtin_amdgcn_sched_barrier(0);
    __builtin_amdgcn_s_barrier();       // WAR release: buf cur free for t+2's stage
  }

  // epilogue: O / l -> Ctx [T][HID]
  if (hi == 0) lred[(w << 5) + l31] = l;
  asm volatile("s_waitcnt lgkmcnt(0)" ::: "memory");
#pragma unroll
  for (int r = 0; r < 16; ++r){
    const int cr = (r & 3) + 8 * (r >> 2) + 4 * hi;
    const float li = 1.f / lred[(w << 5) + cr];
    const int trow = qw0 + cr;
    bf16_t* cb = Ctx + (size_t)trow * HID + h * DHEAD + l31;
#pragma unroll
    for (int nb = 0; nb < 4; ++nb)
      cb[nb << 5] = (bf16_t)(o[nb][r] * li);
  }
}

// ---------------- launcher ----------------
extern "C" void kernel_launch(void* const* d_in, const int* in_sizes, int n_in,
                              void* d_out, int out_size, void* d_ws, size_t ws_size,
                              hipStream_t stream)
{
  const float* X   = (const float*)d_in[0];
  const float* Wq  = (const float*)d_in[2];
  const float* Wk  = (const float*)d_in[3];
  const float* Wv  = (const float*)d_in[4];
  const float* Wo  = (const float*)d_in[5];
  const float* PKi = (const float*)d_in[6];
  const float* PVi = (const float*)d_in[7];
  const int* POS   = (const int*)d_in[8];
  const int* PLEN  = (const int*)d_in[9];
  float* OUT = (float*)d_out;

  char* ws = (char*)d_ws;
  const size_t SZ_XB  = (size_t)T_LEN * HID * 2;             // 16 MiB
  const size_t SZ_W   = (size_t)HID * HID * 2;               // 32 MiB
  const size_t SZ_HTD = (size_t)NHEAD * T_LEN * DHEAD * 2;   // 16 MiB

  bf16_t* XB  = (bf16_t*)(ws);
  bf16_t* WT0 = (bf16_t*)(ws + SZ_XB);
  bf16_t* WT1 = (bf16_t*)(ws + SZ_XB + SZ_W);
  bf16_t* WT2 = (bf16_t*)(ws + SZ_XB + 2 * SZ_W);
  char* p = ws + SZ_XB + 3 * SZ_W;
  bf16_t* QB   = (bf16_t*)p; p += SZ_HTD;
  bf16_t* KB   = (bf16_t*)p; p += SZ_HTD;
  bf16_t* VTB  = (bf16_t*)p; p += SZ_HTD;
  bf16_t* KPB  = (bf16_t*)p; p += SZ_HTD;
  bf16_t* VPTB = (bf16_t*)p; p += SZ_HTD;
  bf16_t* CTX  = (bf16_t*)p; p += SZ_HTD;
  bf16_t* WOT  = QB;   // reuse QB+KB (32 MiB contiguous) after attention

  dim3 blk256(256);
  dim3 blk512(512);
  cvt2_k<<<16384, blk256, 0, stream>>>(X, XB, PKi, KPB, T_LEN * HID / 4);
  transpose3_k<<<dim3(64,64,3), blk256, 0, stream>>>(Wq, Wk, Wv, WT0, WT1, WT2);
  transpose2_k<<<dim3(32,2,32), blk256, 0, stream>>>(PVi, VPTB, PAST_MAX, DHEAD);

  gemmqkv_rr_k<<<768, blk512, 0, stream>>>(XB, WT0, WT1, WT2, QB, KB, VTB, 96);
  ropek_k<<<16384, blk256, 0, stream>>>(KB, POS);
  attn2_k<<<512, blk256, 0, stream>>>(QB, KB, VTB, KPB, VPTB, CTX, PLEN, POS);

  transpose2_k<<<dim3(64,64,1), blk256, 0, stream>>>(Wo, WOT, HID, HID);
  gemmop_rr_k<<<256, blk512, 0, stream>>>(CTX, WOT, OUT, 32);
}

// Round 5
// 562.807 us; speedup vs baseline: 1.0737x; 1.0599x over previous
//
#include <hip/hip_runtime.h>
#include <cstdint>
#include <cstddef>

#define T_LEN 2048
#define PAST_MAX 2048
#define HID 4096
#define NHEAD 32
#define DHEAD 128

typedef __bf16 bf16_t;
typedef __bf16 bf16x4 __attribute__((ext_vector_type(4)));
typedef __bf16 bf16x8 __attribute__((ext_vector_type(8)));
typedef float  f32x4  __attribute__((ext_vector_type(4)));
typedef float  f32x16 __attribute__((ext_vector_type(16)));
typedef unsigned int u32x4 __attribute__((ext_vector_type(4)));

__device__ __forceinline__ void gload16(const void* g, void* l){
  __builtin_amdgcn_global_load_lds((const __attribute__((address_space(1))) void*)g,
                                   (__attribute__((address_space(3))) void*)l,
                                   16, 0, 0);
}

__device__ __forceinline__ unsigned pack_bf16(float a, float b){
  const unsigned ua = __builtin_bit_cast(unsigned short, (bf16_t)a);
  const unsigned ub = __builtin_bit_cast(unsigned short, (bf16_t)b);
  return ua | (ub << 16);
}

// ---------------- fused f32 -> bf16 for X and past_k ----------------
__global__ void cvt2_k(const float* __restrict__ a, bf16_t* __restrict__ ao,
                       const float* __restrict__ b, bf16_t* __restrict__ bo, int n4){
  int i = blockIdx.x * 256 + threadIdx.x;
  if (i < n4){
    const float4 v = ((const float4*)a)[i];
    bf16x4 o = { (bf16_t)v.x, (bf16_t)v.y, (bf16_t)v.z, (bf16_t)v.w };
    ((bf16x4*)ao)[i] = o;
  } else {
    i -= n4;
    const float4 v = ((const float4*)b)[i];
    bf16x4 o = { (bf16_t)v.x, (bf16_t)v.y, (bf16_t)v.z, (bf16_t)v.w };
    ((bf16x4*)bo)[i] = o;
  }
}

// ---------------- f32 [B][R][C] -> bf16 [B][C][R], 64x64 tiles ----------------
__global__ __launch_bounds__(256) void transpose2_k(const float* __restrict__ in,
                                                    bf16_t* __restrict__ out, int R, int C){
  __shared__ float tile[64][65];
  const int r0 = blockIdx.x << 6, c0 = blockIdx.y << 6;
  const size_t bo = (size_t)blockIdx.z * (size_t)R * (size_t)C;
  const int tx = threadIdx.x & 15, ty = threadIdx.x >> 4;
#pragma unroll
  for (int k = 0; k < 4; ++k){
    const float4 v = *(const float4*)(in + bo + (size_t)(r0 + ty + 16*k) * C + c0 + tx*4);
    float* tp = &tile[ty + 16*k][tx*4];
    tp[0] = v.x; tp[1] = v.y; tp[2] = v.z; tp[3] = v.w;
  }
  __syncthreads();
  const int rr0 = (threadIdx.x & 7) * 8;
  const int ccb = threadIdx.x >> 3;     // 0..31
#pragma unroll
  for (int k = 0; k < 2; ++k){
    const int cc = ccb + 32*k;
    bf16x8 o;
#pragma unroll
    for (int j = 0; j < 8; ++j) o[j] = (bf16_t)tile[rr0 + j][cc];
    *(bf16x8*)(out + bo + (size_t)(c0 + cc) * R + r0 + rr0) = o;
  }
}

// ---------------- fused transpose of Wq/Wk/Wv (z selects) ----------------
__global__ __launch_bounds__(256) void transpose3_k(
    const float* __restrict__ s0, const float* __restrict__ s1, const float* __restrict__ s2,
    bf16_t* __restrict__ d0, bf16_t* __restrict__ d1, bf16_t* __restrict__ d2){
  __shared__ float tile[64][65];
  const float* in = (blockIdx.z == 0) ? s0 : (blockIdx.z == 1) ? s1 : s2;
  bf16_t* out = (blockIdx.z == 0) ? d0 : (blockIdx.z == 1) ? d1 : d2;
  const int r0 = blockIdx.x << 6, c0 = blockIdx.y << 6;
  const int tx = threadIdx.x & 15, ty = threadIdx.x >> 4;
#pragma unroll
  for (int k = 0; k < 4; ++k){
    const float4 v = *(const float4*)(in + (size_t)(r0 + ty + 16*k) * HID + c0 + tx*4);
    float* tp = &tile[ty + 16*k][tx*4];
    tp[0] = v.x; tp[1] = v.y; tp[2] = v.z; tp[3] = v.w;
  }
  __syncthreads();
  const int rr0 = (threadIdx.x & 7) * 8;
  const int ccb = threadIdx.x >> 3;
#pragma unroll
  for (int k = 0; k < 2; ++k){
    const int cc = ccb + 32*k;
    bf16x8 o;
#pragma unroll
    for (int j = 0; j < 8; ++j) o[j] = (bf16_t)tile[rr0 + j][cc];
    *(bf16x8*)(out + (size_t)(c0 + cc) * HID + r0 + rr0) = o;
  }
}

// ---------------- RoPE in place on K only (Q roped in-register inside attn) ------------
__global__ void ropek_k(bf16_t* __restrict__ K, const int* __restrict__ pos){
  const int idx = blockIdx.x * 256 + threadIdx.x;     // 32*2048*64 total
  const int i = idx & 63;
  const int t = (idx >> 6) & (T_LEN - 1);
  const int h = idx >> 17;
  const size_t base = ((size_t)h * T_LEN + t) * DHEAD;
  const float p = (float)pos[t];
  const float inv = __expf(-(float)i * 0.14391156605212898f);  // ln(10000)/64
  const float ang = p * inv;
  float sn, cs;
  sincosf(ang, &sn, &cs);
  const float b0 = (float)K[base + i], b1 = (float)K[base + i + 64];
  K[base + i]      = (bf16_t)(b0 * cs - b1 * sn);
  K[base + i + 64] = (bf16_t)(b1 * cs + b0 * sn);
}

// ====================== QKV: 256x256 BK=64 8-phase (m201-faithful) ======================
// Units (16 KB each, one staged per phase): within K-tile buffer (kt&1):
//   A0 = rows {wr*128 + 0..63},  A1 = rows {wr*128 + 64..127}   (both wr halves)
//   B0 = cols {wc*64 + 0..31},   B1 = cols {wc*64 + 32..63}     (all wc stripes)
// Phase/quadrant order per K-tile: (ah,nh) = (0,0),(0,1),(1,1),(1,0)
//   ph1: read A0(8)+B0(4) [B0 held in regs through ph4]; stage A1(kt+1) [other buf]
//   ph2: read B1(4);                                     stage A0(kt+2) [A0 LDS-dead @ph1]
//   ph3: read A1(8) [B1 held];                           stage B0(kt+2) [dead @ph1]
//   ph4: no reads [A1,B0 held];                          stage B1(kt+2) [dead @ph2]
//        + vmcnt(6): newest guaranteed unit = A1(kt+1), consumed next group ph3 (6-ph lead)
// Each phase: [reads | 1-unit stage] -> barrier -> lgkmcnt(0) -> setprio(1) 16 MFMA -> barrier.
// Waves desync through the LDS queue post-barrier (early finishers MFMA under late readers).
// 8 waves 2Mx4N (wave tile 128x64), 24 KB reads/wave/K-tile, LDS 128 KB, 1 block/CU.
#define QUAD16(AH, NH, BF) \
  __builtin_amdgcn_s_setprio(1); \
  _Pragma("unroll") \
  for (int kk = 0; kk < 2; ++kk){ \
    _Pragma("unroll") \
    for (int mf = 0; mf < 4; ++mf){ \
      _Pragma("unroll") \
      for (int ni = 0; ni < 2; ++ni) \
        acc[(AH)*4 + mf][(NH)*2 + ni] = __builtin_amdgcn_mfma_f32_16x16x32_bf16( \
            af[mf][kk], BF[ni][kk], acc[(AH)*4 + mf][(NH)*2 + ni], 0, 0, 0); \
    } \
  } \
  __builtin_amdgcn_s_setprio(0);

__global__ __launch_bounds__(512, 1) void gemmqkv8_k(
    const bf16_t* __restrict__ A,
    const bf16_t* __restrict__ B0p, const bf16_t* __restrict__ B1p, const bf16_t* __restrict__ B2p,
    bf16_t* __restrict__ OQ, bf16_t* __restrict__ OK2, bf16_t* __restrict__ OVT, int cpx)
{
  const int bid = blockIdx.x;
  const int wg  = (bid & 7) * cpx + (bid >> 3);   // cpx = 48; 384 % 8 == 0 -> bijective
  const int mt  = wg & 7;
  const int nt  = wg >> 3;          // 0..47
  const int z   = nt >> 4;
  const int m0  = mt << 8;
  const int n0  = (nt & 15) << 8;
  const bf16_t* __restrict__ B = (z == 0) ? B0p : (z == 1) ? B1p : B2p;

  const int tid = threadIdx.x;
  const int wv = tid >> 6, lane = tid & 63, lm = lane & 15, g = lane >> 4;
  const int wr = wv >> 2, wc = wv & 3;   // 2 M-groups x 4 N-groups (wave tile 128x64)

  __shared__ __align__(16) char smem[131072];  // [buf][A0|A1|B0|B1][16384]

  const f32x4 fzero = {0.f, 0.f, 0.f, 0.f};
  f32x4 acc[8][4];
#pragma unroll
  for (int i = 0; i < 8; ++i)
#pragma unroll
    for (int j = 0; j < 4; ++j) acc[i][j] = fzero;

  // staging decode: unit = 1024 chunks of 16 B; rows 128 B (8 chunks), XOR-swizzled source
  int arow_[2], brow_[2], jcol_[2];
#pragma unroll
  for (int i = 0; i < 2; ++i){
    const int c  = i * 512 + tid;
    const int rl = c >> 3;
    const int j  = (c & 7) ^ (rl & 7);
    arow_[i] = m0 + ((rl >> 6) << 7) + (rl & 63);   // + ah*64
    brow_[i] = n0 + ((rl >> 5) << 6) + (rl & 31);   // + nh*32
    jcol_[i] = j << 3;
  }
  const int ldst0 = ((0 * 512 + wv * 64) << 4);
  const int ldst1 = ((1 * 512 + wv * 64) << 4);

  auto stgA = [&](int kt, int ah){
    if ((unsigned)kt < 64u){
      char* dst = smem + (kt & 1) * 65536 + ah * 16384;
      const bf16_t* base = A + (size_t)kt * 64;
      gload16(base + (size_t)(arow_[0] + ah * 64) * HID + jcol_[0], dst + ldst0);
      gload16(base + (size_t)(arow_[1] + ah * 64) * HID + jcol_[1], dst + ldst1);
    }
  };
  auto stgB = [&](int kt, int nh){
    if ((unsigned)kt < 64u){
      char* dst = smem + (kt & 1) * 65536 + 32768 + nh * 16384;
      const bf16_t* base = B + (size_t)kt * 64;
      gload16(base + (size_t)(brow_[0] + nh * 32) * HID + jcol_[0], dst + ldst0);
      gload16(base + (size_t)(brow_[1] + nh * 32) * HID + jcol_[1], dst + ldst1);
    }
  };

  // fragment read constants: all frag rows == lm (mod 8) -> lane-constant swizzle
  const int koff0 = ((0 + g) ^ (lm & 7)) << 4;
  const int koff1 = ((4 + g) ^ (lm & 7)) << 4;
  const int abase = ((wr << 6) + lm) << 7;   // within A-unit: (wr*64 + mf*16 + lm)*128
  const int bbase = ((wc << 5) + lm) << 7;   // within B-unit: (wc*32 + ni*16 + lm)*128

  // prologue: kt0 fully (4 units) + kt1 A0,B0,B1 (A1(1) staged at group-0 ph1)
  stgA(0, 0); stgB(0, 0); stgB(0, 1); stgA(0, 1);
  stgA(1, 0); stgB(1, 0); stgB(1, 1);
  asm volatile("s_waitcnt vmcnt(6)" ::: "memory");   // kt0's 4 units landed
  __builtin_amdgcn_s_barrier();

  bf16x8 af[4][2], b0f[2][2], b1f[2][2];

  for (int kt = 0; kt < 64; ++kt){
    char* buf = smem + (kt & 1) * 65536;

    // ---- phase 1: quad (0,0); read A0 + B0; stage A1(kt+1) ----
#pragma unroll
    for (int mf = 0; mf < 4; ++mf){
      af[mf][0] = *(const bf16x8*)(buf + abase + mf * 2048 + koff0);
      af[mf][1] = *(const bf16x8*)(buf + abase + mf * 2048 + koff1);
    }
#pragma unroll
    for (int ni = 0; ni < 2; ++ni){
      b0f[ni][0] = *(const bf16x8*)(buf + 32768 + bbase + ni * 2048 + koff0);
      b0f[ni][1] = *(const bf16x8*)(buf + 32768 + bbase + ni * 2048 + koff1);
    }
    stgA(kt + 1, 1);
    __builtin_amdgcn_sched_barrier(0);
    __builtin_amdgcn_s_barrier();
    asm volatile("s_waitcnt lgkmcnt(0)" ::: "memory");
    __builtin_amdgcn_sched_barrier(0);
    QUAD16(0, 0, b0f)
    __builtin_amdgcn_s_barrier();

    // ---- phase 2: quad (0,1); read B1; stage A0(kt+2) ----
#pragma unroll
    for (int ni = 0; ni < 2; ++ni){
      b1f[ni][0] = *(const bf16x8*)(buf + 49152 + bbase + ni * 2048 + koff0);
      b1f[ni][1] = *(const bf16x8*)(buf + 49152 + bbase + ni * 2048 + koff1);
    }
    stgA(kt + 2, 0);
    __builtin_amdgcn_sched_barrier(0);
    __builtin_amdgcn_s_barrier();
    asm volatile("s_waitcnt lgkmcnt(0)" ::: "memory");
    __builtin_amdgcn_sched_barrier(0);
    QUAD16(0, 1, b1f)
    __builtin_amdgcn_s_barrier();

    // ---- phase 3: quad (1,1); read A1; stage B0(kt+2) ----
#pragma unroll
    for (int mf = 0; mf < 4; ++mf){
      af[mf][0] = *(const bf16x8*)(buf + 16384 + abase + mf * 2048 + koff0);
      af[mf][1] = *(const bf16x8*)(buf + 16384 + abase + mf * 2048 + koff1);
    }
    stgB(kt + 2, 0);
    __builtin_amdgcn_sched_barrier(0);
    __builtin_amdgcn_s_barrier();
    asm volatile("s_waitcnt lgkmcnt(0)" ::: "memory");
    __builtin_amdgcn_sched_barrier(0);
    QUAD16(1, 1, b1f)
    __builtin_amdgcn_s_barrier();

    // ---- phase 4: quad (1,0); no reads (A1,B0 held); stage B1(kt+2); counted vmcnt ----
    stgB(kt + 2, 1);
    if (kt < 60) asm volatile("s_waitcnt vmcnt(6)" ::: "memory");   // A1(kt+1) landed
    else         asm volatile("s_waitcnt vmcnt(0)" ::: "memory");   // tail drain
    __builtin_amdgcn_sched_barrier(0);
    __builtin_amdgcn_s_barrier();
    QUAD16(1, 0, b0f)
    __builtin_amdgcn_s_barrier();
  }

  // epilogue: 3-way layout select (Q/K [H][T][D], V^T [H][D][T])
#pragma unroll
  for (int ni4 = 0; ni4 < 4; ++ni4){
    const int col = n0 + wc * 64 + (ni4 >> 1) * 32 + (ni4 & 1) * 16 + lm;
    const int hh = col >> 7, dd = col & 127;
#pragma unroll
    for (int mf8 = 0; mf8 < 8; ++mf8){
      const int trow0 = m0 + wr * 128 + (mf8 >> 2) * 64 + (mf8 & 3) * 16 + g * 4;
      if (z == 2){
        bf16x4 v4 = { (bf16_t)acc[mf8][ni4][0], (bf16_t)acc[mf8][ni4][1],
                      (bf16_t)acc[mf8][ni4][2], (bf16_t)acc[mf8][ni4][3] };
        *(bf16x4*)(OVT + ((size_t)hh * DHEAD + dd) * T_LEN + trow0) = v4;
      } else {
        bf16_t* ob = (z == 1) ? OK2 : OQ;
#pragma unroll
        for (int r = 0; r < 4; ++r)
          ob[((size_t)hh * T_LEN + trow0 + r) * DHEAD + dd] = (bf16_t)acc[mf8][ni4][r];
      }
    }
  }
}

// ------------- out-proj: 256x128 4-phase interleaved GEMM (R15-proven, 4Mx2N) ----------
__global__ __launch_bounds__(512, 1) void gemm4p_k(
    const bf16_t* __restrict__ A, const bf16_t* __restrict__ B,
    float* __restrict__ OF, int cpx)
{
  const int bid = blockIdx.x;
  const int wg  = (bid & 7) * cpx + (bid >> 3);
  const int mt  = wg & 7;
  const int nt  = wg >> 3;
  const int m0  = mt << 8;
  const int n0  = nt << 7;

  const int tid = threadIdx.x;
  const int wv = tid >> 6, lane = tid & 63, lm = lane & 15, g = lane >> 4;
  const int wr = wv >> 1, wc = wv & 1;      // 4 M-groups x 2 N-groups

  __shared__ __align__(16) char smem[98304];

  const f32x4 fzero = {0.f, 0.f, 0.f, 0.f};
  f32x4 acc[4][4];
#pragma unroll
  for (int i = 0; i < 4; ++i)
#pragma unroll
    for (int j = 0; j < 4; ++j) acc[i][j] = fzero;

  // staging: op = 16 KB = 1024 chunks (128 rows x 8); 2 loads/thread
  int srow[2], schk[2];
#pragma unroll
  for (int i = 0; i < 2; ++i){
    const int c = i * 512 + tid;
    srow[i] = c >> 3;
    schk[i] = (c & 7) ^ (srow[i] & 7);
  }
  const int sdst0 = ((0 * 512 + wv * 64) << 4);
  const int sdst1 = ((1 * 512 + wv * 64) << 4);

  // ops: 0 = A rows 0-127, 1 = A rows 128-255, 2 = B rows 0-127
  auto stg = [&](int kt, int op){
    if (kt < 64){
      char* dst = smem + (kt & 1) * 49152 + op * 16384;
      const bf16_t* base = (op < 2) ? A + (size_t)(m0 + (op << 7)) * HID
                                    : B + (size_t)n0 * HID;
      base += kt * 64;
      gload16(base + (size_t)srow[0] * HID + schk[0] * 8, dst + sdst0);
      gload16(base + (size_t)srow[1] * HID + schk[1] * 8, dst + sdst1);
    }
  };

  // fragment read constants (all frag rows == lm mod 8 -> same swizzle)
  const int koff0 = ((g)     ^ (lm & 7)) << 4;
  const int koff1 = ((4 + g) ^ (lm & 7)) << 4;
  const int abase = ((wr >> 1) << 14) + ((((wr & 1) << 6) + lm) << 7);
  const int bbase = 32768 + ((((wc << 6)) + lm) << 7);

  bf16x8 bfr[4][2];
  auto dsB = [&](int buf){
    const char* p = smem + buf * 49152 + bbase;
#pragma unroll
    for (int ni = 0; ni < 4; ++ni){
      bfr[ni][0] = *(const bf16x8*)(p + ni * 2048 + koff0);
      bfr[ni][1] = *(const bf16x8*)(p + ni * 2048 + koff1);
    }
  };

  // prologue: B(0), A(0), B(1); force B(0)+A(0), keep B(1) in flight
  stg(0, 2);
  stg(0, 0); stg(0, 1);
  stg(1, 2);
  asm volatile("s_waitcnt vmcnt(2)" ::: "memory");
  __builtin_amdgcn_s_barrier();

  for (int t = 0; t < 32; ++t){
    const int c0 = 2 * t, c1 = 2 * t + 1;
    const bool last = (t == 31);

#pragma unroll
    for (int half = 0; half < 2; ++half){
      const char* bufp = smem + half * 49152;
      bf16x8 afr[2][2];
      dsB(half);
#pragma unroll
      for (int mf = 0; mf < 2; ++mf){
        afr[mf][0] = *(const bf16x8*)(bufp + abase + mf * 2048 + koff0);
        afr[mf][1] = *(const bf16x8*)(bufp + abase + mf * 2048 + koff1);
      }
      if (half == 0){ stg(c1, 0); stg(c1, 1); }
      else          { stg(c0 + 2, 0); stg(c0 + 2, 1); }
      __builtin_amdgcn_s_barrier();
      asm volatile("s_waitcnt lgkmcnt(0)" ::: "memory");
      __builtin_amdgcn_s_setprio(1);
#pragma unroll
      for (int kk = 0; kk < 2; ++kk)
#pragma unroll
        for (int mf = 0; mf < 2; ++mf)
#pragma unroll
          for (int ni = 0; ni < 4; ++ni)
            acc[mf][ni] = __builtin_amdgcn_mfma_f32_16x16x32_bf16(afr[mf][kk], bfr[ni][kk], acc[mf][ni], 0, 0, 0);
      __builtin_amdgcn_s_setprio(0);
      __builtin_amdgcn_s_barrier();

#pragma unroll
      for (int mf = 0; mf < 2; ++mf){
        afr[mf][0] = *(const bf16x8*)(bufp + abase + (mf + 2) * 2048 + koff0);
        afr[mf][1] = *(const bf16x8*)(bufp + abase + (mf + 2) * 2048 + koff1);
      }
      if (half == 0) stg(c0 + 2, 2);
      else           stg(c1 + 2, 2);
      if (last) asm volatile("s_waitcnt vmcnt(0)" ::: "memory");
      else      asm volatile("s_waitcnt vmcnt(2)" ::: "memory");
      __builtin_amdgcn_s_barrier();
      asm volatile("s_waitcnt lgkmcnt(0)" ::: "memory");
      __builtin_amdgcn_s_setprio(1);
#pragma unroll
      for (int kk = 0; kk < 2; ++kk)
#pragma unroll
        for (int mf = 0; mf < 2; ++mf)
#pragma unroll
          for (int ni = 0; ni < 4; ++ni)
            acc[mf + 2][ni] = __builtin_amdgcn_mfma_f32_16x16x32_bf16(afr[mf][kk], bfr[ni][kk], acc[mf + 2][ni], 0, 0, 0);
      __builtin_amdgcn_s_setprio(0);
      __builtin_amdgcn_s_barrier();
    }
  }

  // epilogue
#pragma unroll
  for (int ni = 0; ni < 4; ++ni){
    const int col = n0 + wc * 64 + ni * 16 + lm;
#pragma unroll
    for (int mf = 0; mf < 4; ++mf)
#pragma unroll
      for (int r = 0; r < 4; ++r){
        const int trow = m0 + wr * 64 + mf * 16 + g * 4 + r;
        OF[(size_t)trow * HID + col] = acc[mf][ni][r];
      }
  }
}

// ---------------- flash attention: 32x32 MFMA, counted-vmcnt KV pipeline ----------------
// Q roped+scaled in-register (per-lane pair d <-> d+64 lives in qf[dc] / qf[dc+4]).
__global__ __launch_bounds__(256, 2) void attn2_k(
    const bf16_t* __restrict__ Q,
    const bf16_t* __restrict__ Kc,
    const bf16_t* __restrict__ VTc,
    const bf16_t* __restrict__ Kp,
    const bf16_t* __restrict__ VTp,
    bf16_t* __restrict__ Ctx,
    const int* __restrict__ plen_p,
    const int* __restrict__ pos)
{
  // XCD-chunked + complementary-qb balance remap (bijective)
  const int bid = blockIdx.x;          // 0..511
  const int xcd = bid & 7;
  const int k   = bid >> 3;            // 0..63
  const int ho  = k >> 4;              // 0..3
  const int qraw= k & 15;
  const int h   = (xcd << 2) | ho;
  const int qb  = (ho & 2) ? (15 - qraw) : qraw;

  const int tid = threadIdx.x;
  const int w = tid >> 6, lane = tid & 63, l31 = lane & 31, hi = lane >> 5;
  const int qw0 = qb * 128 + w * 32;
  const int qrow = qw0 + l31;
  const int plen = plen_p[0];
  const int npast = (plen + 63) >> 6;
  const int NT = npast + 2 * qb + 2;

  __shared__ __align__(16) char smem[65536 + 512];
  float* lred = (float*)(smem + 65536);   // per-wave 32-float broadcast slice

  // Q fragments from global; rope+scale in-register (consumes loads before stage(0))
  const bf16_t* qbase = Q + ((size_t)h * T_LEN + qrow) * DHEAD;
  bf16x8 qf[8];
#pragma unroll
  for (int dc = 0; dc < 8; ++dc)
    qf[dc] = *(const bf16x8*)(qbase + dc * 16 + 8 * hi);
  {
    const float ppos = (float)pos[qrow];
    const float qs = 0.08838834764831845f;   // 1/sqrt(128)
#pragma unroll
    for (int dc = 0; dc < 4; ++dc)
#pragma unroll
      for (int j = 0; j < 8; ++j){
        const int fi = dc * 16 + 8 * hi + j;               // freq index = d (< 64)
        const float invf = __expf(-(float)fi * 0.14391156605212898f);
        float sn, cs;
        sincosf(ppos * invf, &sn, &cs);
        const float a0 = (float)qf[dc][j], a1 = (float)qf[dc + 4][j];
        qf[dc][j]     = (bf16_t)((a0 * cs - a1 * sn) * qs);
        qf[dc + 4][j] = (bf16_t)((a1 * cs + a0 * sn) * qs);
      }
  }
  __builtin_amdgcn_sched_barrier(0);

  const f32x16 fz = {0.f,0.f,0.f,0.f,0.f,0.f,0.f,0.f,0.f,0.f,0.f,0.f,0.f,0.f,0.f,0.f};
  f32x16 o[4] = {fz, fz, fz, fz};
  float m = -1e30f, l = 0.f;

  auto stage = [&](int t, int buf){
    const bf16_t* kb; const bf16_t* vb;
    if (t < npast){
      const int s0 = t * 64;
      kb = Kp  + ((size_t)h * PAST_MAX + s0) * DHEAD;
      vb = VTp + (size_t)h * DHEAD * PAST_MAX + s0;
    } else {
      const int s0 = (t - npast) * 64;
      kb = Kc  + ((size_t)h * T_LEN + s0) * DHEAD;
      vb = VTc + (size_t)h * DHEAD * T_LEN + s0;
    }
    char* kl = smem + buf * 32768;
    char* vl = kl + 16384;
#pragma unroll
    for (int i = 0; i < 4; ++i){
      const int c = i * 256 + w * 64 + lane;
      const int krow = c >> 4, kcol = c & 15;          // K [64][128] bf16, 16 chunks/row
      gload16(kb + (size_t)krow * DHEAD + ((kcol ^ (krow & 7)) << 3), kl + (i * 256 + w * 64) * 16);
      const int vrow = c >> 3, vcol = c & 7;           // V^T [128][64] bf16, 8 chunks/row
      gload16(vb + (size_t)vrow * 2048 + ((vcol ^ (vrow & 7)) << 3), vl + (i * 256 + w * 64) * 16);
    }
  };

  stage(0, 0);
  __builtin_amdgcn_sched_barrier(0);

  for (int t = 0; t < NT; ++t){
    const int cur = t & 1;
    if (t + 1 < NT){
      stage(t + 1, cur ^ 1);
      asm volatile("s_waitcnt vmcnt(8)" ::: "memory");   // tile t landed; t+1 in flight
    } else {
      asm volatile("s_waitcnt vmcnt(0)" ::: "memory");
    }
    __builtin_amdgcn_sched_barrier(0);
    __builtin_amdgcn_s_barrier();
    __builtin_amdgcn_sched_barrier(0);

    const bool isc = (t >= npast);
    const int s0c = (t - npast) * 64;
    const bool active = !isc || (s0c <= qw0 + 31);

    if (active){
      char* kl = smem + cur * 32768;
      char* vl = kl + 16384;

      f32x16 sacc[2] = {fz, fz};
      __builtin_amdgcn_s_setprio(1);
#pragma unroll
      for (int kvh = 0; kvh < 2; ++kvh){
        const int krow = (kvh << 5) + l31;
        const int kbo = krow << 8;
        const int sw = (krow & 7) << 4;
#pragma unroll
        for (int dc = 0; dc < 8; ++dc){
          const bf16x8 kf = *(const bf16x8*)(kl + kbo + ((dc * 32 + 16 * hi) ^ sw));
          sacc[kvh] = __builtin_amdgcn_mfma_f32_32x32x16_bf16(kf, qf[dc], sacc[kvh], 0, 0, 0);
        }
      }
      __builtin_amdgcn_s_setprio(0);

      // mask-hoist: only diagonal/boundary tiles pay the per-element mask chain
      const bool mcur  = isc && (s0c + 63 > qw0);
      const bool mpast = !isc && ((t + 1) * 64 > plen);
      float pv[2][16];
      float pm = -1e30f;
      if (mcur | mpast){
#pragma unroll
        for (int kvh = 0; kvh < 2; ++kvh)
#pragma unroll
          for (int r = 0; r < 16; ++r){
            float x = sacc[kvh][r];
            const int kvoff = (kvh << 5) + (r & 3) + 8 * (r >> 2) + 4 * hi;
            if (mcur  && (s0c + kvoff >  qrow)) x = -1e30f;
            if (mpast && (t * 64 + kvoff >= plen)) x = -1e30f;
            pv[kvh][r] = x;
            pm = fmaxf(pm, x);
          }
      } else {
#pragma unroll
        for (int kvh = 0; kvh < 2; ++kvh)
#pragma unroll
          for (int r = 0; r < 16; ++r){
            pv[kvh][r] = sacc[kvh][r];
            pm = fmaxf(pm, sacc[kvh][r]);
          }
      }
      pm = fmaxf(pm, __shfl_xor(pm, 32));

      // defer-max: rescale only when max grows past threshold
      if (!__all(pm - m <= 8.f)){
        const float mn = fmaxf(m, pm);
        const float corr = __expf(m - mn);
        m = mn;
        l *= corr;
        if (hi == 0) lred[(w << 5) + l31] = corr;
        asm volatile("s_waitcnt lgkmcnt(0)" ::: "memory");
#pragma unroll
        for (int r = 0; r < 16; ++r){
          const float cc = lred[(w << 5) + (r & 3) + 8 * (r >> 2) + 4 * hi];
#pragma unroll
          for (int nb = 0; nb < 4; ++nb) o[nb][r] *= cc;
        }
      }

      float sum = 0.f;
#pragma unroll
      for (int kvh = 0; kvh < 2; ++kvh)
#pragma unroll
        for (int r = 0; r < 16; ++r){
          const float pe = __expf(pv[kvh][r] - m);
          pv[kvh][r] = pe;
          sum += pe;
        }
      sum += __shfl_xor(sum, 32);
      l += sum;

      // pack own 32 P to 16 words; partner-exchange 8 words -> PV A-frags
      unsigned wds[2][8];
#pragma unroll
      for (int kvh = 0; kvh < 2; ++kvh)
#pragma unroll
        for (int i = 0; i < 8; ++i)
          wds[kvh][i] = pack_bf16(pv[kvh][2 * i], pv[kvh][2 * i + 1]);

      bf16x8 pf[4];
#pragma unroll
      for (int ks = 0; ks < 4; ++ks){
        const int s = ks & 1, kvh = ks >> 1;
        const unsigned a0 = hi ? wds[kvh][4 * s]     : wds[kvh][4 * s + 2];
        const unsigned a1 = hi ? wds[kvh][4 * s + 1] : wds[kvh][4 * s + 3];
        const unsigned z0 = (unsigned)__shfl_xor((int)a0, 32);
        const unsigned z1 = (unsigned)__shfl_xor((int)a1, 32);
        u32x4 fw;
        fw[0] = hi ? z0 : wds[kvh][4 * s];
        fw[1] = hi ? z1 : wds[kvh][4 * s + 1];
        fw[2] = hi ? wds[kvh][4 * s + 2] : z0;
        fw[3] = hi ? wds[kvh][4 * s + 3] : z1;
        pf[ks] = __builtin_bit_cast(bf16x8, fw);
      }

      // PV: O[q][dv] += P·V, V^T frags from LDS
      __builtin_amdgcn_s_setprio(1);
#pragma unroll
      for (int ks = 0; ks < 4; ++ks)
#pragma unroll
        for (int nb = 0; nb < 4; ++nb){
          const int vrow = (nb << 5) + l31;
          const bf16x8 vf = *(const bf16x8*)(vl + (vrow << 7) + ((ks * 32 + 16 * hi) ^ ((vrow & 7) << 4)));
          o[nb] = __builtin_amdgcn_mfma_f32_32x32x16_bf16(pf[ks], vf, o[nb], 0, 0, 0);
        }
      __builtin_amdgcn_s_setprio(0);
    }
    __builtin_amdgcn_sched_barrier(0);
    __builtin_amdgcn_s_barrier();       // WAR release: buf cur free for t+2's stage
  }

  // epilogue: O / l -> Ctx [T][HID]
  if (hi == 0) lred[(w << 5) + l31] = l;
  asm volatile("s_waitcnt lgkmcnt(0)" ::: "memory");
#pragma unroll
  for (int r = 0; r < 16; ++r){
    const int cr = (r & 3) + 8 * (r >> 2) + 4 * hi;
    const float li = 1.f / lred[(w << 5) + cr];
    const int trow = qw0 + cr;
    bf16_t* cb = Ctx + (size_t)trow * HID + h * DHEAD + l31;
#pragma unroll
    for (int nb = 0; nb < 4; ++nb)
      cb[nb << 5] = (bf16_t)(o[nb][r] * li);
  }
}

// ---------------- launcher ----------------
extern "C" void kernel_launch(void* const* d_in, const int* in_sizes, int n_in,
                              void* d_out, int out_size, void* d_ws, size_t ws_size,
                              hipStream_t stream)
{
  const float* X   = (const float*)d_in[0];
  const float* Wq  = (const float*)d_in[2];
  const float* Wk  = (const float*)d_in[3];
  const float* Wv  = (const float*)d_in[4];
  const float* Wo  = (const float*)d_in[5];
  const float* PKi = (const float*)d_in[6];
  const float* PVi = (const float*)d_in[7];
  const int* POS   = (const int*)d_in[8];
  const int* PLEN  = (const int*)d_in[9];
  float* OUT = (float*)d_out;

  char* ws = (char*)d_ws;
  const size_t SZ_XB  = (size_t)T_LEN * HID * 2;             // 16 MiB
  const size_t SZ_W   = (size_t)HID * HID * 2;               // 32 MiB
  const size_t SZ_HTD = (size_t)NHEAD * T_LEN * DHEAD * 2;   // 16 MiB

  bf16_t* XB  = (bf16_t*)(ws);
  bf16_t* WT0 = (bf16_t*)(ws + SZ_XB);
  bf16_t* WT1 = (bf16_t*)(ws + SZ_XB + SZ_W);
  bf16_t* WT2 = (bf16_t*)(ws + SZ_XB + 2 * SZ_W);
  char* p = ws + SZ_XB + 3 * SZ_W;
  bf16_t* QB   = (bf16_t*)p; p += SZ_HTD;
  bf16_t* KB   = (bf16_t*)p; p += SZ_HTD;
  bf16_t* VTB  = (bf16_t*)p; p += SZ_HTD;
  bf16_t* KPB  = (bf16_t*)p; p += SZ_HTD;
  bf16_t* VPTB = (bf16_t*)p; p += SZ_HTD;
  bf16_t* CTX  = (bf16_t*)p; p += SZ_HTD;
  bf16_t* WOT  = QB;   // reuse QB+KB (32 MiB contiguous) after attention

  dim3 blk256(256);
  dim3 blk512(512);
  cvt2_k<<<16384, blk256, 0, stream>>>(X, XB, PKi, KPB, T_LEN * HID / 4);
  transpose3_k<<<dim3(64,64,3), blk256, 0, stream>>>(Wq, Wk, Wv, WT0, WT1, WT2);
  transpose2_k<<<dim3(32,2,32), blk256, 0, stream>>>(PVi, VPTB, PAST_MAX, DHEAD);

  gemmqkv8_k<<<384, blk512, 0, stream>>>(XB, WT0, WT1, WT2, QB, KB, VTB, 48);
  ropek_k<<<16384, blk256, 0, stream>>>(KB, POS);
  attn2_k<<<512, blk256, 0, stream>>>(QB, KB, VTB, KPB, VPTB, CTX, PLEN, POS);

  transpose2_k<<<dim3(64,64,1), blk256, 0, stream>>>(Wo, WOT, HID, HID);
  gemm4p_k<<<256, blk512, 0, stream>>>(CTX, WOT, OUT, 32);
}

// Round 6
// 535.351 us; speedup vs baseline: 1.1288x; 1.0513x over previous
//
#include <hip/hip_runtime.h>
#include <cstdint>
#include <cstddef>

#define T_LEN 2048
#define PAST_MAX 2048
#define HID 4096
#define NHEAD 32
#define DHEAD 128

typedef __bf16 bf16_t;
typedef __bf16 bf16x4 __attribute__((ext_vector_type(4)));
typedef __bf16 bf16x8 __attribute__((ext_vector_type(8)));
typedef float  f32x4  __attribute__((ext_vector_type(4)));
typedef float  f32x16 __attribute__((ext_vector_type(16)));
typedef unsigned int u32x4 __attribute__((ext_vector_type(4)));

__device__ __forceinline__ void gload16(const void* g, void* l){
  __builtin_amdgcn_global_load_lds((const __attribute__((address_space(1))) void*)g,
                                   (__attribute__((address_space(3))) void*)l,
                                   16, 0, 0);
}

__device__ __forceinline__ unsigned pack_bf16(float a, float b){
  const unsigned ua = __builtin_bit_cast(unsigned short, (bf16_t)a);
  const unsigned ub = __builtin_bit_cast(unsigned short, (bf16_t)b);
  return ua | (ub << 16);
}

// ---------------- fused f32 -> bf16 for X and past_k ----------------
__global__ void cvt2_k(const float* __restrict__ a, bf16_t* __restrict__ ao,
                       const float* __restrict__ b, bf16_t* __restrict__ bo, int n4){
  int i = blockIdx.x * 256 + threadIdx.x;
  if (i < n4){
    const float4 v = ((const float4*)a)[i];
    bf16x4 o = { (bf16_t)v.x, (bf16_t)v.y, (bf16_t)v.z, (bf16_t)v.w };
    ((bf16x4*)ao)[i] = o;
  } else {
    i -= n4;
    const float4 v = ((const float4*)b)[i];
    bf16x4 o = { (bf16_t)v.x, (bf16_t)v.y, (bf16_t)v.z, (bf16_t)v.w };
    ((bf16x4*)bo)[i] = o;
  }
}

// ---------------- f32 [B][R][C] -> bf16 [B][C][R], 64x64 tiles ----------------
__global__ __launch_bounds__(256) void transpose2_k(const float* __restrict__ in,
                                                    bf16_t* __restrict__ out, int R, int C){
  __shared__ float tile[64][65];
  const int r0 = blockIdx.x << 6, c0 = blockIdx.y << 6;
  const size_t bo = (size_t)blockIdx.z * (size_t)R * (size_t)C;
  const int tx = threadIdx.x & 15, ty = threadIdx.x >> 4;
#pragma unroll
  for (int k = 0; k < 4; ++k){
    const float4 v = *(const float4*)(in + bo + (size_t)(r0 + ty + 16*k) * C + c0 + tx*4);
    float* tp = &tile[ty + 16*k][tx*4];
    tp[0] = v.x; tp[1] = v.y; tp[2] = v.z; tp[3] = v.w;
  }
  __syncthreads();
  const int rr0 = (threadIdx.x & 7) * 8;
  const int ccb = threadIdx.x >> 3;     // 0..31
#pragma unroll
  for (int k = 0; k < 2; ++k){
    const int cc = ccb + 32*k;
    bf16x8 o;
#pragma unroll
    for (int j = 0; j < 8; ++j) o[j] = (bf16_t)tile[rr0 + j][cc];
    *(bf16x8*)(out + bo + (size_t)(c0 + cc) * R + r0 + rr0) = o;
  }
}

// ---------------- fused transpose of Wq/Wk/Wv (z selects) ----------------
__global__ __launch_bounds__(256) void transpose3_k(
    const float* __restrict__ s0, const float* __restrict__ s1, const float* __restrict__ s2,
    bf16_t* __restrict__ d0, bf16_t* __restrict__ d1, bf16_t* __restrict__ d2){
  __shared__ float tile[64][65];
  const float* in = (blockIdx.z == 0) ? s0 : (blockIdx.z == 1) ? s1 : s2;
  bf16_t* out = (blockIdx.z == 0) ? d0 : (blockIdx.z == 1) ? d1 : d2;
  const int r0 = blockIdx.x << 6, c0 = blockIdx.y << 6;
  const int tx = threadIdx.x & 15, ty = threadIdx.x >> 4;
#pragma unroll
  for (int k = 0; k < 4; ++k){
    const float4 v = *(const float4*)(in + (size_t)(r0 + ty + 16*k) * HID + c0 + tx*4);
    float* tp = &tile[ty + 16*k][tx*4];
    tp[0] = v.x; tp[1] = v.y; tp[2] = v.z; tp[3] = v.w;
  }
  __syncthreads();
  const int rr0 = (threadIdx.x & 7) * 8;
  const int ccb = threadIdx.x >> 3;
#pragma unroll
  for (int k = 0; k < 2; ++k){
    const int cc = ccb + 32*k;
    bf16x8 o;
#pragma unroll
    for (int j = 0; j < 8; ++j) o[j] = (bf16_t)tile[rr0 + j][cc];
    *(bf16x8*)(out + (size_t)(c0 + cc) * HID + r0 + rr0) = o;
  }
}

// ---------------- RoPE in place on K only (Q roped in-register inside attn) ------------
__global__ void ropek_k(bf16_t* __restrict__ K, const int* __restrict__ pos){
  const int idx = blockIdx.x * 256 + threadIdx.x;     // 32*2048*64 total
  const int i = idx & 63;
  const int t = (idx >> 6) & (T_LEN - 1);
  const int h = idx >> 17;
  const size_t base = ((size_t)h * T_LEN + t) * DHEAD;
  const float p = (float)pos[t];
  const float inv = __expf(-(float)i * 0.14391156605212898f);  // ln(10000)/64
  const float ang = p * inv;
  float sn, cs;
  sincosf(ang, &sn, &cs);
  const float b0 = (float)K[base + i], b1 = (float)K[base + i + 64];
  K[base + i]      = (bf16_t)(b0 * cs - b1 * sn);
  K[base + i + 64] = (bf16_t)(b1 * cs + b0 * sn);
}

// =============== QKV: 128x384 BK=64, 3-phase unit-liveness, 512 blocks = 2 EXACT gens ===
// R5 post-mortem: 8-phase 256^2 achieved 46% in-gen MFMA but grid 384 = 1.5 generations
// (makespan 2*tau, gen-2 half idle) -> 36.9% average. Fix: B treated as the CONCATENATED
// [12288][4096] (WT0|WT1|WT2 are contiguous in workspace); tile 128x384 -> grid 16x32 =
// 512 blocks = exactly 2 full generations at 1 block/CU. Same unit-liveness schedule as
// R5: per K-tile 3 phases {A+B0 | B1 | B2} x 16 MFMA; stage B2(kt+1)@ph1 (other buf),
// A(kt+2)@ph2, B0/B1(kt+2)@ph3 (each unit staged only after its last-read phase barrier);
// one counted vmcnt(6)/K-tile (6 newest outstanding = kt+2's A,B0,B1 -> kt+1 landed).
// 8 waves 2Mx4N (wave 64x96), acc[4][6], ~160 VGPR, LDS 2 x 64KB.
// Units are 16KB = 1024 chunks, 2 gload16/thread; B-unit pr = cols {(c%96)/32 == pr}.
#define QUAD384(PR, BF) \
  __builtin_amdgcn_s_setprio(1); \
  _Pragma("unroll") \
  for (int kk = 0; kk < 2; ++kk){ \
    _Pragma("unroll") \
    for (int mf = 0; mf < 4; ++mf){ \
      _Pragma("unroll") \
      for (int ni = 0; ni < 2; ++ni) \
        acc[mf][(PR)*2 + ni] = __builtin_amdgcn_mfma_f32_16x16x32_bf16( \
            af[mf][kk], BF[ni][kk], acc[mf][(PR)*2 + ni], 0, 0, 0); \
    } \
  } \
  __builtin_amdgcn_s_setprio(0);

__global__ __launch_bounds__(512, 1) void gemmqkv384_k(
    const bf16_t* __restrict__ A,
    const bf16_t* __restrict__ Bc,       // concatenated W^T: [12288][4096]
    bf16_t* __restrict__ OQ, bf16_t* __restrict__ OK2, bf16_t* __restrict__ OVT)
{
  const int bid = blockIdx.x;
  const int wg  = (bid & 7) * 64 + (bid >> 3);   // 512 % 8 == 0 -> bijective XCD chunking
  const int mt  = wg & 15;                        // 16 M-tiles of 128
  const int nt  = wg >> 4;                        // 32 N-tiles of 384
  const int m0  = mt << 7;
  const int n0g = nt * 384;

  const int tid = threadIdx.x;
  const int wv = tid >> 6, lane = tid & 63, lm = lane & 15, g = lane >> 4;
  const int wr = wv >> 2, wc = wv & 3;   // 2 M-groups x 4 N-groups (wave tile 64x96)

  __shared__ __align__(16) char smem[131072];  // [buf][ A 16K | B0 16K | B1 16K | B2 16K ]

  const f32x4 fzero = {0.f, 0.f, 0.f, 0.f};
  f32x4 acc[4][6];
#pragma unroll
  for (int i = 0; i < 4; ++i)
#pragma unroll
    for (int j = 0; j < 6; ++j) acc[i][j] = fzero;

  // staging decode: unit = 1024 chunks of 16B, 8 chunks per 128B row; source pre-swizzled
  size_t aoff[2], boff[2];
#pragma unroll
  for (int i = 0; i < 2; ++i){
    const int c = i * 512 + tid;
    const int u = c >> 3;                       // row-within-unit 0..127
    const int j = ((c & 7) ^ (u & 7)) << 3;     // element offset of 16B chunk
    aoff[i] = (size_t)(m0 + u) * HID + j;
    const int bcol = (u >> 5) * 96 + (u & 31);  // + pr*32 at call
    boff[i] = (size_t)(n0g + bcol) * HID + j;
  }
  const int ldst0 = (wv * 64) << 4;             // + lane*16 implicit
  const int ldst1 = (512 + wv * 64) << 4;

  auto stgA = [&](char* buf, int kt){
    const bf16_t* src = A + (size_t)kt * 64;
    gload16(src + aoff[0], buf + ldst0);
    gload16(src + aoff[1], buf + ldst1);
  };
  auto stgB = [&](char* buf, int kt, int pr){
    const bf16_t* src = Bc + (size_t)kt * 64 + (size_t)pr * (32 * HID);
    char* dst = buf + 16384 + pr * 16384;
    gload16(src + boff[0], dst + ldst0);
    gload16(src + boff[1], dst + ldst1);
  };

  // fragment read constants (frag rows == lm mod 8 -> lane-constant swizzle)
  const int koff0 = ((0 + g) ^ (lm & 7)) << 4;
  const int koff1 = ((4 + g) ^ (lm & 7)) << 4;
  const int abase = ((wr << 6) + lm) << 7;      // (wr*64 + lm)*128, + mf*2048
  const int bbase = ((wc << 5) + lm) << 7;      // (wc*32 + lm)*128, + ni*2048 (in unit pr)

  // prologue: kt0 fully + kt1 {A,B0,B1}; retire kt0 (vmcnt(6) leaves kt1's 6 in flight)
  stgA(smem, 0); stgB(smem, 0, 0); stgB(smem, 0, 1); stgB(smem, 0, 2);
  stgA(smem + 65536, 1); stgB(smem + 65536, 1, 0); stgB(smem + 65536, 1, 1);
  asm volatile("s_waitcnt vmcnt(6)" ::: "memory");
  __builtin_amdgcn_s_barrier();

  bf16x8 af[4][2], bf[2][2];

  for (int kt = 0; kt < 64; ++kt){
    char* buf  = smem + (kt & 1) * 65536;
    char* obuf = smem + ((kt + 1) & 1) * 65536;

    // ---- phase 1: read A(8) + B0(4); stage B2(kt+1) into other buf ----
#pragma unroll
    for (int mf = 0; mf < 4; ++mf){
      af[mf][0] = *(const bf16x8*)(buf + abase + mf * 2048 + koff0);
      af[mf][1] = *(const bf16x8*)(buf + abase + mf * 2048 + koff1);
    }
#pragma unroll
    for (int ni = 0; ni < 2; ++ni){
      bf[ni][0] = *(const bf16x8*)(buf + 16384 + bbase + ni * 2048 + koff0);
      bf[ni][1] = *(const bf16x8*)(buf + 16384 + bbase + ni * 2048 + koff1);
    }
    if (kt + 1 < 64) stgB(obuf, kt + 1, 2);
    __builtin_amdgcn_sched_barrier(0);
    __builtin_amdgcn_s_barrier();
    asm volatile("s_waitcnt lgkmcnt(0)" ::: "memory");
    __builtin_amdgcn_sched_barrier(0);
    QUAD384(0, bf)
    __builtin_amdgcn_s_barrier();

    // ---- phase 2: read B1(4); stage A(kt+2) (A(kt) dead after ph1) ----
#pragma unroll
    for (int ni = 0; ni < 2; ++ni){
      bf[ni][0] = *(const bf16x8*)(buf + 32768 + bbase + ni * 2048 + koff0);
      bf[ni][1] = *(const bf16x8*)(buf + 32768 + bbase + ni * 2048 + koff1);
    }
    if (kt + 2 < 64) stgA(buf, kt + 2);
    __builtin_amdgcn_sched_barrier(0);
    __builtin_amdgcn_s_barrier();
    asm volatile("s_waitcnt lgkmcnt(0)" ::: "memory");
    __builtin_amdgcn_sched_barrier(0);
    QUAD384(1, bf)
    __builtin_amdgcn_s_barrier();

    // ---- phase 3: read B2(4); stage B0/B1(kt+2); counted vmcnt publishes kt+1 ----
#pragma unroll
    for (int ni = 0; ni < 2; ++ni){
      bf[ni][0] = *(const bf16x8*)(buf + 49152 + bbase + ni * 2048 + koff0);
      bf[ni][1] = *(const bf16x8*)(buf + 49152 + bbase + ni * 2048 + koff1);
    }
    if (kt + 2 < 64){ stgB(buf, kt + 2, 0); stgB(buf, kt + 2, 1); }
    __builtin_amdgcn_sched_barrier(0);
    __builtin_amdgcn_s_barrier();
    asm volatile("s_waitcnt lgkmcnt(0)" ::: "memory");
    __builtin_amdgcn_sched_barrier(0);
    QUAD384(2, bf)
    if (kt <= 61) asm volatile("s_waitcnt vmcnt(6)" ::: "memory");
    else          asm volatile("s_waitcnt vmcnt(0)" ::: "memory");
    __builtin_amdgcn_sched_barrier(0);
    __builtin_amdgcn_s_barrier();
  }

  // epilogue: per-16-col-block z select (blocks never straddle 4096 boundaries)
#pragma unroll
  for (int pr = 0; pr < 3; ++pr)
#pragma unroll
    for (int ni = 0; ni < 2; ++ni){
      const int colg = n0g + wc * 96 + pr * 32 + ni * 16 + lm;
      const int z  = colg >> 12;
      const int wi = colg & 4095;
      const int hh = wi >> 7, dd = wi & 127;
      const int ai = pr * 2 + ni;
#pragma unroll
      for (int mf = 0; mf < 4; ++mf){
        const int trow0 = m0 + wr * 64 + mf * 16 + g * 4;
        if (z == 2){
          bf16x4 v4 = { (bf16_t)acc[mf][ai][0], (bf16_t)acc[mf][ai][1],
                        (bf16_t)acc[mf][ai][2], (bf16_t)acc[mf][ai][3] };
          *(bf16x4*)(OVT + ((size_t)hh * DHEAD + dd) * T_LEN + trow0) = v4;
        } else {
          bf16_t* ob = z ? OK2 : OQ;
#pragma unroll
          for (int r = 0; r < 4; ++r)
            ob[((size_t)hh * T_LEN + trow0 + r) * DHEAD + dd] = (bf16_t)acc[mf][ai][r];
        }
      }
    }
}

// ------------- out-proj: 256x128 4-phase interleaved GEMM (R15-proven, 4Mx2N) ----------
__global__ __launch_bounds__(512, 1) void gemm4p_k(
    const bf16_t* __restrict__ A, const bf16_t* __restrict__ B,
    float* __restrict__ OF, int cpx)
{
  const int bid = blockIdx.x;
  const int wg  = (bid & 7) * cpx + (bid >> 3);
  const int mt  = wg & 7;
  const int nt  = wg >> 3;
  const int m0  = mt << 8;
  const int n0  = nt << 7;

  const int tid = threadIdx.x;
  const int wv = tid >> 6, lane = tid & 63, lm = lane & 15, g = lane >> 4;
  const int wr = wv >> 1, wc = wv & 1;      // 4 M-groups x 2 N-groups

  __shared__ __align__(16) char smem[98304];

  const f32x4 fzero = {0.f, 0.f, 0.f, 0.f};
  f32x4 acc[4][4];
#pragma unroll
  for (int i = 0; i < 4; ++i)
#pragma unroll
    for (int j = 0; j < 4; ++j) acc[i][j] = fzero;

  // staging: op = 16 KB = 1024 chunks (128 rows x 8); 2 loads/thread
  int srow[2], schk[2];
#pragma unroll
  for (int i = 0; i < 2; ++i){
    const int c = i * 512 + tid;
    srow[i] = c >> 3;
    schk[i] = (c & 7) ^ (srow[i] & 7);
  }
  const int sdst0 = ((0 * 512 + wv * 64) << 4);
  const int sdst1 = ((1 * 512 + wv * 64) << 4);

  // ops: 0 = A rows 0-127, 1 = A rows 128-255, 2 = B rows 0-127
  auto stg = [&](int kt, int op){
    if (kt < 64){
      char* dst = smem + (kt & 1) * 49152 + op * 16384;
      const bf16_t* base = (op < 2) ? A + (size_t)(m0 + (op << 7)) * HID
                                    : B + (size_t)n0 * HID;
      base += kt * 64;
      gload16(base + (size_t)srow[0] * HID + schk[0] * 8, dst + sdst0);
      gload16(base + (size_t)srow[1] * HID + schk[1] * 8, dst + sdst1);
    }
  };

  // fragment read constants (all frag rows == lm mod 8 -> same swizzle)
  const int koff0 = ((g)     ^ (lm & 7)) << 4;
  const int koff1 = ((4 + g) ^ (lm & 7)) << 4;
  const int abase = ((wr >> 1) << 14) + ((((wr & 1) << 6) + lm) << 7);
  const int bbase = 32768 + ((((wc << 6)) + lm) << 7);

  bf16x8 bfr[4][2];
  auto dsB = [&](int buf){
    const char* p = smem + buf * 49152 + bbase;
#pragma unroll
    for (int ni = 0; ni < 4; ++ni){
      bfr[ni][0] = *(const bf16x8*)(p + ni * 2048 + koff0);
      bfr[ni][1] = *(const bf16x8*)(p + ni * 2048 + koff1);
    }
  };

  // prologue: B(0), A(0), B(1); force B(0)+A(0), keep B(1) in flight
  stg(0, 2);
  stg(0, 0); stg(0, 1);
  stg(1, 2);
  asm volatile("s_waitcnt vmcnt(2)" ::: "memory");
  __builtin_amdgcn_s_barrier();

  for (int t = 0; t < 32; ++t){
    const int c0 = 2 * t, c1 = 2 * t + 1;
    const bool last = (t == 31);

#pragma unroll
    for (int half = 0; half < 2; ++half){
      const char* bufp = smem + half * 49152;
      bf16x8 afr[2][2];
      dsB(half);
#pragma unroll
      for (int mf = 0; mf < 2; ++mf){
        afr[mf][0] = *(const bf16x8*)(bufp + abase + mf * 2048 + koff0);
        afr[mf][1] = *(const bf16x8*)(bufp + abase + mf * 2048 + koff1);
      }
      if (half == 0){ stg(c1, 0); stg(c1, 1); }
      else          { stg(c0 + 2, 0); stg(c0 + 2, 1); }
      __builtin_amdgcn_s_barrier();
      asm volatile("s_waitcnt lgkmcnt(0)" ::: "memory");
      __builtin_amdgcn_s_setprio(1);
#pragma unroll
      for (int kk = 0; kk < 2; ++kk)
#pragma unroll
        for (int mf = 0; mf < 2; ++mf)
#pragma unroll
          for (int ni = 0; ni < 4; ++ni)
            acc[mf][ni] = __builtin_amdgcn_mfma_f32_16x16x32_bf16(afr[mf][kk], bfr[ni][kk], acc[mf][ni], 0, 0, 0);
      __builtin_amdgcn_s_setprio(0);
      __builtin_amdgcn_s_barrier();

#pragma unroll
      for (int mf = 0; mf < 2; ++mf){
        afr[mf][0] = *(const bf16x8*)(bufp + abase + (mf + 2) * 2048 + koff0);
        afr[mf][1] = *(const bf16x8*)(bufp + abase + (mf + 2) * 2048 + koff1);
      }
      if (half == 0) stg(c0 + 2, 2);
      else           stg(c1 + 2, 2);
      if (last) asm volatile("s_waitcnt vmcnt(0)" ::: "memory");
      else      asm volatile("s_waitcnt vmcnt(2)" ::: "memory");
      __builtin_amdgcn_s_barrier();
      asm volatile("s_waitcnt lgkmcnt(0)" ::: "memory");
      __builtin_amdgcn_s_setprio(1);
#pragma unroll
      for (int kk = 0; kk < 2; ++kk)
#pragma unroll
        for (int mf = 0; mf < 2; ++mf)
#pragma unroll
          for (int ni = 0; ni < 4; ++ni)
            acc[mf + 2][ni] = __builtin_amdgcn_mfma_f32_16x16x32_bf16(afr[mf][kk], bfr[ni][kk], acc[mf + 2][ni], 0, 0, 0);
      __builtin_amdgcn_s_setprio(0);
      __builtin_amdgcn_s_barrier();
    }
  }

  // epilogue
#pragma unroll
  for (int ni = 0; ni < 4; ++ni){
    const int col = n0 + wc * 64 + ni * 16 + lm;
#pragma unroll
    for (int mf = 0; mf < 4; ++mf)
#pragma unroll
      for (int r = 0; r < 4; ++r){
        const int trow = m0 + wr * 64 + mf * 16 + g * 4 + r;
        OF[(size_t)trow * HID + col] = acc[mf][ni][r];
      }
  }
}

// ---------------- flash attention: 32x32 MFMA, counted-vmcnt KV pipeline ----------------
// Q roped+scaled in-register (per-lane pair d <-> d+64 lives in qf[dc] / qf[dc+4]).
__global__ __launch_bounds__(256, 2) void attn2_k(
    const bf16_t* __restrict__ Q,
    const bf16_t* __restrict__ Kc,
    const bf16_t* __restrict__ VTc,
    const bf16_t* __restrict__ Kp,
    const bf16_t* __restrict__ VTp,
    bf16_t* __restrict__ Ctx,
    const int* __restrict__ plen_p,
    const int* __restrict__ pos)
{
  // XCD-chunked + complementary-qb balance remap (bijective)
  const int bid = blockIdx.x;          // 0..511
  const int xcd = bid & 7;
  const int k   = bid >> 3;            // 0..63
  const int ho  = k >> 4;              // 0..3
  const int qraw= k & 15;
  const int h   = (xcd << 2) | ho;
  const int qb  = (ho & 2) ? (15 - qraw) : qraw;

  const int tid = threadIdx.x;
  const int w = tid >> 6, lane = tid & 63, l31 = lane & 31, hi = lane >> 5;
  const int qw0 = qb * 128 + w * 32;
  const int qrow = qw0 + l31;
  const int plen = plen_p[0];
  const int npast = (plen + 63) >> 6;
  const int NT = npast + 2 * qb + 2;

  __shared__ __align__(16) char smem[65536 + 512];
  float* lred = (float*)(smem + 65536);   // per-wave 32-float broadcast slice

  // Q fragments from global; rope+scale in-register (consumes loads before stage(0))
  const bf16_t* qbase = Q + ((size_t)h * T_LEN + qrow) * DHEAD;
  bf16x8 qf[8];
#pragma unroll
  for (int dc = 0; dc < 8; ++dc)
    qf[dc] = *(const bf16x8*)(qbase + dc * 16 + 8 * hi);
  {
    const float ppos = (float)pos[qrow];
    const float qs = 0.08838834764831845f;   // 1/sqrt(128)
#pragma unroll
    for (int dc = 0; dc < 4; ++dc)
#pragma unroll
      for (int j = 0; j < 8; ++j){
        const int fi = dc * 16 + 8 * hi + j;               // freq index = d (< 64)
        const float invf = __expf(-(float)fi * 0.14391156605212898f);
        float sn, cs;
        sincosf(ppos * invf, &sn, &cs);
        const float a0 = (float)qf[dc][j], a1 = (float)qf[dc + 4][j];
        qf[dc][j]     = (bf16_t)((a0 * cs - a1 * sn) * qs);
        qf[dc + 4][j] = (bf16_t)((a1 * cs + a0 * sn) * qs);
      }
  }
  __builtin_amdgcn_sched_barrier(0);

  const f32x16 fz = {0.f,0.f,0.f,0.f,0.f,0.f,0.f,0.f,0.f,0.f,0.f,0.f,0.f,0.f,0.f,0.f};
  f32x16 o[4] = {fz, fz, fz, fz};
  float m = -1e30f, l = 0.f;

  auto stage = [&](int t, int buf){
    const bf16_t* kb; const bf16_t* vb;
    if (t < npast){
      const int s0 = t * 64;
      kb = Kp  + ((size_t)h * PAST_MAX + s0) * DHEAD;
      vb = VTp + (size_t)h * DHEAD * PAST_MAX + s0;
    } else {
      const int s0 = (t - npast) * 64;
      kb = Kc  + ((size_t)h * T_LEN + s0) * DHEAD;
      vb = VTc + (size_t)h * DHEAD * T_LEN + s0;
    }
    char* kl = smem + buf * 32768;
    char* vl = kl + 16384;
#pragma unroll
    for (int i = 0; i < 4; ++i){
      const int c = i * 256 + w * 64 + lane;
      const int krow = c >> 4, kcol = c & 15;          // K [64][128] bf16, 16 chunks/row
      gload16(kb + (size_t)krow * DHEAD + ((kcol ^ (krow & 7)) << 3), kl + (i * 256 + w * 64) * 16);
      const int vrow = c >> 3, vcol = c & 7;           // V^T [128][64] bf16, 8 chunks/row
      gload16(vb + (size_t)vrow * 2048 + ((vcol ^ (vrow & 7)) << 3), vl + (i * 256 + w * 64) * 16);
    }
  };

  stage(0, 0);
  __builtin_amdgcn_sched_barrier(0);

  for (int t = 0; t < NT; ++t){
    const int cur = t & 1;
    if (t + 1 < NT){
      stage(t + 1, cur ^ 1);
      asm volatile("s_waitcnt vmcnt(8)" ::: "memory");   // tile t landed; t+1 in flight
    } else {
      asm volatile("s_waitcnt vmcnt(0)" ::: "memory");
    }
    __builtin_amdgcn_sched_barrier(0);
    __builtin_amdgcn_s_barrier();
    __builtin_amdgcn_sched_barrier(0);

    const bool isc = (t >= npast);
    const int s0c = (t - npast) * 64;
    const bool active = !isc || (s0c <= qw0 + 31);

    if (active){
      char* kl = smem + cur * 32768;
      char* vl = kl + 16384;

      f32x16 sacc[2] = {fz, fz};
      __builtin_amdgcn_s_setprio(1);
#pragma unroll
      for (int kvh = 0; kvh < 2; ++kvh){
        const int krow = (kvh << 5) + l31;
        const int kbo = krow << 8;
        const int sw = (krow & 7) << 4;
#pragma unroll
        for (int dc = 0; dc < 8; ++dc){
          const bf16x8 kf = *(const bf16x8*)(kl + kbo + ((dc * 32 + 16 * hi) ^ sw));
          sacc[kvh] = __builtin_amdgcn_mfma_f32_32x32x16_bf16(kf, qf[dc], sacc[kvh], 0, 0, 0);
        }
      }
      __builtin_amdgcn_s_setprio(0);

      // mask-hoist: only diagonal/boundary tiles pay the per-element mask chain
      const bool mcur  = isc && (s0c + 63 > qw0);
      const bool mpast = !isc && ((t + 1) * 64 > plen);
      float pv[2][16];
      float pm = -1e30f;
      if (mcur | mpast){
#pragma unroll
        for (int kvh = 0; kvh < 2; ++kvh)
#pragma unroll
          for (int r = 0; r < 16; ++r){
            float x = sacc[kvh][r];
            const int kvoff = (kvh << 5) + (r & 3) + 8 * (r >> 2) + 4 * hi;
            if (mcur  && (s0c + kvoff >  qrow)) x = -1e30f;
            if (mpast && (t * 64 + kvoff >= plen)) x = -1e30f;
            pv[kvh][r] = x;
            pm = fmaxf(pm, x);
          }
      } else {
#pragma unroll
        for (int kvh = 0; kvh < 2; ++kvh)
#pragma unroll
          for (int r = 0; r < 16; ++r){
            pv[kvh][r] = sacc[kvh][r];
            pm = fmaxf(pm, sacc[kvh][r]);
          }
      }
      pm = fmaxf(pm, __shfl_xor(pm, 32));

      // defer-max: rescale only when max grows past threshold
      if (!__all(pm - m <= 8.f)){
        const float mn = fmaxf(m, pm);
        const float corr = __expf(m - mn);
        m = mn;
        l *= corr;
        if (hi == 0) lred[(w << 5) + l31] = corr;
        asm volatile("s_waitcnt lgkmcnt(0)" ::: "memory");
#pragma unroll
        for (int r = 0; r < 16; ++r){
          const float cc = lred[(w << 5) + (r & 3) + 8 * (r >> 2) + 4 * hi];
#pragma unroll
          for (int nb = 0; nb < 4; ++nb) o[nb][r] *= cc;
        }
      }

      float sum = 0.f;
#pragma unroll
      for (int kvh = 0; kvh < 2; ++kvh)
#pragma unroll
        for (int r = 0; r < 16; ++r){
          const float pe = __expf(pv[kvh][r] - m);
          pv[kvh][r] = pe;
          sum += pe;
        }
      sum += __shfl_xor(sum, 32);
      l += sum;

      // pack own 32 P to 16 words; partner-exchange 8 words -> PV A-frags
      unsigned wds[2][8];
#pragma unroll
      for (int kvh = 0; kvh < 2; ++kvh)
#pragma unroll
        for (int i = 0; i < 8; ++i)
          wds[kvh][i] = pack_bf16(pv[kvh][2 * i], pv[kvh][2 * i + 1]);

      bf16x8 pf[4];
#pragma unroll
      for (int ks = 0; ks < 4; ++ks){
        const int s = ks & 1, kvh = ks >> 1;
        const unsigned a0 = hi ? wds[kvh][4 * s]     : wds[kvh][4 * s + 2];
        const unsigned a1 = hi ? wds[kvh][4 * s + 1] : wds[kvh][4 * s + 3];
        const unsigned z0 = (unsigned)__shfl_xor((int)a0, 32);
        const unsigned z1 = (unsigned)__shfl_xor((int)a1, 32);
        u32x4 fw;
        fw[0] = hi ? z0 : wds[kvh][4 * s];
        fw[1] = hi ? z1 : wds[kvh][4 * s + 1];
        fw[2] = hi ? wds[kvh][4 * s + 2] : z0;
        fw[3] = hi ? wds[kvh][4 * s + 3] : z1;
        pf[ks] = __builtin_bit_cast(bf16x8, fw);
      }

      // PV: O[q][dv] += P·V, V^T frags from LDS
      __builtin_amdgcn_s_setprio(1);
#pragma unroll
      for (int ks = 0; ks < 4; ++ks)
#pragma unroll
        for (int nb = 0; nb < 4; ++nb){
          const int vrow = (nb << 5) + l31;
          const bf16x8 vf = *(const bf16x8*)(vl + (vrow << 7) + ((ks * 32 + 16 * hi) ^ ((vrow & 7) << 4)));
          o[nb] = __builtin_amdgcn_mfma_f32_32x32x16_bf16(pf[ks], vf, o[nb], 0, 0, 0);
        }
      __builtin_amdgcn_s_setprio(0);
    }
    __builtin_amdgcn_sched_barrier(0);
    __builtin_amdgcn_s_barrier();       // WAR release: buf cur free for t+2's stage
  }

  // epilogue: O / l -> Ctx [T][HID]
  if (hi == 0) lred[(w << 5) + l31] = l;
  asm volatile("s_waitcnt lgkmcnt(0)" ::: "memory");
#pragma unroll
  for (int r = 0; r < 16; ++r){
    const int cr = (r & 3) + 8 * (r >> 2) + 4 * hi;
    const float li = 1.f / lred[(w << 5) + cr];
    const int trow = qw0 + cr;
    bf16_t* cb = Ctx + (size_t)trow * HID + h * DHEAD + l31;
#pragma unroll
    for (int nb = 0; nb < 4; ++nb)
      cb[nb << 5] = (bf16_t)(o[nb][r] * li);
  }
}

// ---------------- launcher ----------------
extern "C" void kernel_launch(void* const* d_in, const int* in_sizes, int n_in,
                              void* d_out, int out_size, void* d_ws, size_t ws_size,
                              hipStream_t stream)
{
  const float* X   = (const float*)d_in[0];
  const float* Wq  = (const float*)d_in[2];
  const float* Wk  = (const float*)d_in[3];
  const float* Wv  = (const float*)d_in[4];
  const float* Wo  = (const float*)d_in[5];
  const float* PKi = (const float*)d_in[6];
  const float* PVi = (const float*)d_in[7];
  const int* POS   = (const int*)d_in[8];
  const int* PLEN  = (const int*)d_in[9];
  float* OUT = (float*)d_out;

  char* ws = (char*)d_ws;
  const size_t SZ_XB  = (size_t)T_LEN * HID * 2;             // 16 MiB
  const size_t SZ_W   = (size_t)HID * HID * 2;               // 32 MiB
  const size_t SZ_HTD = (size_t)NHEAD * T_LEN * DHEAD * 2;   // 16 MiB

  bf16_t* XB  = (bf16_t*)(ws);
  bf16_t* WT0 = (bf16_t*)(ws + SZ_XB);                       // WT0|WT1|WT2 contiguous:
  bf16_t* WT1 = (bf16_t*)(ws + SZ_XB + SZ_W);                // concatenated B [12288][4096]
  bf16_t* WT2 = (bf16_t*)(ws + SZ_XB + 2 * SZ_W);
  char* p = ws + SZ_XB + 3 * SZ_W;
  bf16_t* QB   = (bf16_t*)p; p += SZ_HTD;
  bf16_t* KB   = (bf16_t*)p; p += SZ_HTD;
  bf16_t* VTB  = (bf16_t*)p; p += SZ_HTD;
  bf16_t* KPB  = (bf16_t*)p; p += SZ_HTD;
  bf16_t* VPTB = (bf16_t*)p; p += SZ_HTD;
  bf16_t* CTX  = (bf16_t*)p; p += SZ_HTD;
  bf16_t* WOT  = QB;   // reuse QB+KB (32 MiB contiguous) after attention

  dim3 blk256(256);
  dim3 blk512(512);
  cvt2_k<<<16384, blk256, 0, stream>>>(X, XB, PKi, KPB, T_LEN * HID / 4);
  transpose3_k<<<dim3(64,64,3), blk256, 0, stream>>>(Wq, Wk, Wv, WT0, WT1, WT2);
  transpose2_k<<<dim3(32,2,32), blk256, 0, stream>>>(PVi, VPTB, PAST_MAX, DHEAD);

  gemmqkv384_k<<<512, blk512, 0, stream>>>(XB, WT0, QB, KB, VTB);
  ropek_k<<<16384, blk256, 0, stream>>>(KB, POS);
  attn2_k<<<512, blk256, 0, stream>>>(QB, KB, VTB, KPB, VPTB, CTX, PLEN, POS);

  transpose2_k<<<dim3(64,64,1), blk256, 0, stream>>>(Wo, WOT, HID, HID);
  gemm4p_k<<<256, blk512, 0, stream>>>(CTX, WOT, OUT, 32);
}